// Round 1
// baseline (1030.515 us; speedup 1.0000x reference)
//
#include <hip/hip_runtime.h>

// ---------------------------------------------------------------------------
// Enhanced_transformer  B=8, N=4096, P=1024, P4=256  (all fp32 in/out)
//
//  h   = LN1(x)                      -> f32 (for logit path) + bf16 (for xv)
//  Qt  = qk_w @ h^T                  f32 VALU GEMM      [B,256,4096]
//  xv  = h @ v_w^T + v_b             bf16 MFMA          [B*N,1024] bf16
//  en  = Qt @ Qt^T                   f32 VALU, splitK=8 [B,256,256]
//  G   = gelu(t1_w @ en + t1_b)      f32 VALU           [B,1024,256]
//  a2  = t2_w @ G^T + t2_b           f32 VALU           [B,1024,1024]
//  attT= softmax(a2,-1) transposed   -> bf16            [B,1024,1024]
//  x1  = xv @ attT^T + x             bf16 MFMA, f32 out
//  h2  = LN2(x1)                     -> bf16
//  g   = gelu(h2 @ m1_w^T + m1_b)    bf16 MFMA
//  out = x1 + g @ m2_w^T + m2_b      bf16 MFMA, f32 out
//
// Logit path stays fp32: softmax logits have sigma~190 over 1024 entries
// (near-argmax); bf16 there -> O(1) logit error -> absmax ~1-3 > 0.289.
// Value/MLP path bf16 errors enter linearly (~0.05 absmax) -> safe.
// ---------------------------------------------------------------------------

typedef __attribute__((ext_vector_type(4))) float f32x4;
typedef __attribute__((ext_vector_type(8))) short s16x8;
typedef __attribute__((ext_vector_type(8))) unsigned short u16x8;
typedef __attribute__((ext_vector_type(4))) unsigned short u16x4;

__device__ __forceinline__ unsigned short f2bf(float f) {
  unsigned u = __float_as_uint(f);
  u += 0x7fffu + ((u >> 16) & 1u);          // round-to-nearest-even
  return (unsigned short)(u >> 16);
}
__device__ __forceinline__ float gelu_f(float x) {
  return 0.5f * x * (1.0f + erff(x * 0.70710678118654752f));
}
__device__ __forceinline__ void gload16(const void* g, void* l) {
  __builtin_amdgcn_global_load_lds(
      (const __attribute__((address_space(1))) unsigned int*)g,
      (__attribute__((address_space(3))) unsigned int*)l, 16, 0, 0);
}

// ---------------- LayerNorm (one row of 1024 per block, 256 thr) -----------
__global__ __launch_bounds__(256)
void ln_kernel(const float* __restrict__ x, const float* __restrict__ g,
               const float* __restrict__ b, float* __restrict__ outf,
               unsigned short* __restrict__ outb) {
  __shared__ float red[16];
  const size_t base = (size_t)blockIdx.x * 1024;
  const int t = threadIdx.x;
  f32x4 v = *(const f32x4*)&x[base + t * 4];
  float s = v[0] + v[1] + v[2] + v[3];
  float q = v[0] * v[0] + v[1] * v[1] + v[2] * v[2] + v[3] * v[3];
#pragma unroll
  for (int o = 32; o > 0; o >>= 1) { s += __shfl_down(s, o); q += __shfl_down(q, o); }
  const int w = t >> 6;
  if ((t & 63) == 0) { red[w] = s; red[8 + w] = q; }
  __syncthreads();
  s = (red[0] + red[1]) + (red[2] + red[3]);
  q = (red[8] + red[9]) + (red[10] + red[11]);
  const float mu = s * (1.0f / 1024.0f);
  const float var = q * (1.0f / 1024.0f) - mu * mu;
  const float is = rsqrtf(var + 1e-5f);
  f32x4 gg = *(const f32x4*)&g[t * 4];
  f32x4 bb = *(const f32x4*)&b[t * 4];
  f32x4 y;
  u16x4 ob;
#pragma unroll
  for (int j = 0; j < 4; j++) { y[j] = (v[j] - mu) * is * gg[j] + bb[j]; ob[j] = f2bf(y[j]); }
  if (outf) *(f32x4*)&outf[base + t * 4] = y;
  *(u16x4*)&outb[base + t * 4] = ob;
}

// ---------------- fp32 -> bf16 cast --------------------------------------
__global__ __launch_bounds__(256)
void cvt_bf16_kernel(const float* __restrict__ in, unsigned short* __restrict__ out, int n4) {
  int i = blockIdx.x * 256 + threadIdx.x;
  if (i < n4) {
    f32x4 v = *(const f32x4*)&in[(size_t)i * 4];
    u16x4 o;
#pragma unroll
    for (int j = 0; j < 4; j++) o[j] = f2bf(v[j]);
    *(u16x4*)&out[(size_t)i * 4] = o;
  }
}

// ---------------- fp32 VALU GEMM: C = A(MxK) * B(NxK)^T --------------------
// 128x128 tile, BK=16, 256 thr, 8x8 microtile.
// EPI: 0 = store, 1 = +bias[row], gelu, 2 = +bias[row]
template <int EPI>
__global__ __launch_bounds__(256)
void gemm_f32(const float* __restrict__ Ain, const float* __restrict__ Bin,
              float* __restrict__ Cout, const float* __restrict__ bias,
              int K, int lda, int ldb, int ldc,
              long long sA, long long sB, long long sC, int splitK) {
  __shared__ float As[16][132];
  __shared__ float Bs[16][132];
  const int z = blockIdx.z;
  const int bi = z / splitK, sp = z % splitK;
  const int kLen = K / splitK, kStart = sp * kLen;
  const float* A = Ain + (size_t)bi * sA;
  const float* B = Bin + (size_t)bi * sB;
  float* C = Cout + (size_t)z * sC;
  const int mBase = blockIdx.y * 128, nBase = blockIdx.x * 128;
  const int t = threadIdx.x;
  const int mld = t >> 2, kq = t & 3;
  const int tr = t >> 4, tc = t & 15;
  float acc[8][8] = {};
  for (int k0 = kStart; k0 < kStart + kLen; k0 += 16) {
    f32x4 va0 = *(const f32x4*)&A[(size_t)(mBase + mld) * lda + k0 + kq * 4];
    f32x4 va1 = *(const f32x4*)&A[(size_t)(mBase + 64 + mld) * lda + k0 + kq * 4];
    f32x4 vb0 = *(const f32x4*)&B[(size_t)(nBase + mld) * ldb + k0 + kq * 4];
    f32x4 vb1 = *(const f32x4*)&B[(size_t)(nBase + 64 + mld) * ldb + k0 + kq * 4];
    __syncthreads();
#pragma unroll
    for (int j = 0; j < 4; j++) {
      As[kq * 4 + j][mld] = va0[j];  As[kq * 4 + j][64 + mld] = va1[j];
      Bs[kq * 4 + j][mld] = vb0[j];  Bs[kq * 4 + j][64 + mld] = vb1[j];
    }
    __syncthreads();
#pragma unroll
    for (int k = 0; k < 16; k++) {
      f32x4 ra0 = *(const f32x4*)&As[k][tr * 8];
      f32x4 ra1 = *(const f32x4*)&As[k][tr * 8 + 4];
      f32x4 rb0 = *(const f32x4*)&Bs[k][tc * 8];
      f32x4 rb1 = *(const f32x4*)&Bs[k][tc * 8 + 4];
      float ra[8] = {ra0[0], ra0[1], ra0[2], ra0[3], ra1[0], ra1[1], ra1[2], ra1[3]};
      float rb[8] = {rb0[0], rb0[1], rb0[2], rb0[3], rb1[0], rb1[1], rb1[2], rb1[3]};
#pragma unroll
      for (int i = 0; i < 8; i++)
#pragma unroll
        for (int j = 0; j < 8; j++) acc[i][j] = fmaf(ra[i], rb[j], acc[i][j]);
    }
  }
#pragma unroll
  for (int i = 0; i < 8; i++) {
    const int rw = mBase + tr * 8 + i;
    const float bv = (EPI >= 1) ? bias[rw] : 0.0f;
    f32x4 o0, o1;
#pragma unroll
    for (int j = 0; j < 4; j++) {
      float v0 = acc[i][j] + bv;
      float v1 = acc[i][j + 4] + bv;
      if (EPI == 1) { v0 = gelu_f(v0); v1 = gelu_f(v1); }
      o0[j] = v0; o1[j] = v1;
    }
    *(f32x4*)&C[(size_t)rw * ldc + nBase + tc * 8] = o0;
    *(f32x4*)&C[(size_t)rw * ldc + nBase + tc * 8 + 4] = o1;
  }
}

// ---------------- bf16 MFMA GEMM: C = A(MxK) * B(NxK)^T --------------------
// 128x128 tile, BK=64, 4 waves each 64x64 (4x4 frags of 16x16x32).
// Staging via global_load_lds (16B), XOR chunk-swizzle on source+read.
// EPI: 0 = bf16 out, +bias[col]
//      1 = bf16 out, +bias[col], gelu
//      2 = f32 out, +res
//      3 = f32 out, +bias[col], +res
template <int EPI>
__global__ __launch_bounds__(256)
void gemm_bf16(const unsigned short* __restrict__ Ain, const unsigned short* __restrict__ Bin,
               void* __restrict__ Cout, const float* __restrict__ bias,
               const float* __restrict__ resIn,
               int K, int lda, int ldb, int ldc,
               long long sA, long long sB, long long sC, long long sRes) {
  __shared__ short As[128 * 64];
  __shared__ short Bs[128 * 64];
  const int z = blockIdx.z;
  const unsigned short* A = Ain + (size_t)z * sA;
  const unsigned short* B = Bin + (size_t)z * sB;
  const int mBase = blockIdx.y * 128, nBase = blockIdx.x * 128;
  const int t = threadIdx.x, w = t >> 6, l = t & 63;
  const int r16 = l & 15, kq = l >> 4;
  const int wr = (w >> 1) * 64, wc = (w & 1) * 64;
  f32x4 acc[4][4] = {};

  for (int k0 = 0; k0 < K; k0 += 64) {
#pragma unroll
    for (int it = 0; it < 4; ++it) {
      const int c = it * 256 + t;              // per-lane chunk id (8 bf16 each)
      const int row = c >> 3, cc = c & 7;
      const int gc = cc ^ (row & 7);           // source-side swizzle
      const int cbase = it * 256 + w * 64;     // wave-uniform LDS base chunk
      gload16(&A[(size_t)(mBase + row) * lda + k0 + gc * 8], &As[cbase * 8]);
      gload16(&B[(size_t)(nBase + row) * ldb + k0 + gc * 8], &Bs[cbase * 8]);
    }
    asm volatile("s_waitcnt vmcnt(0)" ::: "memory");
    __syncthreads();
#pragma unroll
    for (int kk = 0; kk < 2; ++kk) {
      s16x8 aF[4], bF[4];
#pragma unroll
      for (int mi = 0; mi < 4; mi++) {
        const int r = wr + mi * 16 + r16;
        const int cc = (kk * 4 + kq) ^ (r & 7);  // read-side swizzle (same involution)
        aF[mi] = *(const s16x8*)&As[r * 64 + cc * 8];
      }
#pragma unroll
      for (int ni = 0; ni < 4; ni++) {
        const int r = wc + ni * 16 + r16;
        const int cc = (kk * 4 + kq) ^ (r & 7);
        bF[ni] = *(const s16x8*)&Bs[r * 64 + cc * 8];
      }
#pragma unroll
      for (int mi = 0; mi < 4; mi++)
#pragma unroll
        for (int ni = 0; ni < 4; ni++)
          acc[mi][ni] = __builtin_amdgcn_mfma_f32_16x16x32_bf16(aF[mi], bF[ni], acc[mi][ni], 0, 0, 0);
    }
    __syncthreads();
  }

  unsigned short* C16 = (unsigned short*)Cout + (size_t)z * sC;
  float* C32 = (float*)Cout + (size_t)z * sC;
  const float* res = (EPI >= 2) ? (resIn + (size_t)z * sRes) : nullptr;
#pragma unroll
  for (int mi = 0; mi < 4; mi++) {
#pragma unroll
    for (int ni = 0; ni < 4; ni++) {
      const int cl = nBase + wc + ni * 16 + r16;
      float bv = 0.0f;
      if (EPI != 2) bv = bias[cl];
#pragma unroll
      for (int r = 0; r < 4; r++) {
        const int rw = mBase + wr + mi * 16 + kq * 4 + r;   // C/D: row=(l>>4)*4+r, col=l&15
        float v = acc[mi][ni][r] + bv;
        if (EPI == 1) v = gelu_f(v);
        if (EPI >= 2) v += res[(size_t)rw * ldc + cl];
        if (EPI <= 1) C16[(size_t)rw * ldc + cl] = f2bf(v);
        else          C32[(size_t)rw * ldc + cl] = v;
      }
    }
  }
}

// ---------------- energy split-K reduce ------------------------------------
__global__ __launch_bounds__(256)
void ereduce_kernel(const float* __restrict__ part, float* __restrict__ en) {
  const size_t idx = (size_t)blockIdx.x * 256 + threadIdx.x;  // 8*65536 total
  const size_t b = idx >> 16, i = idx & 65535;
  const float* p = part + b * (8ull * 65536) + i;
  float s0 = (p[0] + p[65536]) + (p[2 * 65536] + p[3 * 65536]);
  float s1 = (p[4 * 65536] + p[5 * 65536]) + (p[6 * 65536] + p[7 * 65536]);
  en[idx] = s0 + s1;
}

// ---------------- softmax over rows + transpose -> bf16 --------------------
// block: 8 rows (o) x 1024 (k) of a2[b]; writes attT[b][k][o0..o0+7]
__global__ __launch_bounds__(256)
void smax_t_kernel(const float* __restrict__ a2, unsigned short* __restrict__ attT) {
  __shared__ float S[8][1028];
  __shared__ float inv[8];
  const int t = threadIdx.x;
  const int b = blockIdx.y;
  const int o0 = blockIdx.x * 8;
  const float* src = a2 + ((size_t)b * 1024 + o0) * 1024;
#pragma unroll
  for (int i = 0; i < 8; i++)
    *(f32x4*)&S[i][t * 4] = *(const f32x4*)&src[(size_t)i * 1024 + t * 4];
  __syncthreads();
  const int w = t >> 6, l = t & 63;
  for (int rr = 0; rr < 2; rr++) {
    const int r = w * 2 + rr;
    float m = -1e30f;
#pragma unroll
    for (int i = 0; i < 16; i++) m = fmaxf(m, S[r][l + i * 64]);
#pragma unroll
    for (int o = 32; o > 0; o >>= 1) m = fmaxf(m, __shfl_xor(m, o));
    float ssum = 0.0f;
#pragma unroll
    for (int i = 0; i < 16; i++) {
      float e = expf(S[r][l + i * 64] - m);
      S[r][l + i * 64] = e;
      ssum += e;
    }
#pragma unroll
    for (int o = 32; o > 0; o >>= 1) ssum += __shfl_xor(ssum, o);
    if (l == 0) inv[r] = 1.0f / ssum;
  }
  __syncthreads();
  float iv[8];
#pragma unroll
  for (int r = 0; r < 8; r++) iv[r] = inv[r];
#pragma unroll
  for (int i = 0; i < 4; i++) {
    const int k = i * 256 + t;
    u16x8 ov;
#pragma unroll
    for (int r = 0; r < 8; r++) ov[r] = f2bf(S[r][k] * iv[r]);
    *(u16x8*)&attT[((size_t)b * 1024 + k) * 1024 + o0] = ov;
  }
}

// ---------------------------------------------------------------------------
extern "C" void kernel_launch(void* const* d_in, const int* in_sizes, int n_in,
                              void* d_out, int out_size, void* d_ws, size_t ws_size,
                              hipStream_t stream) {
  (void)in_sizes; (void)n_in; (void)out_size; (void)ws_size;
  const float* x     = (const float*)d_in[1];
  const float* ln1_g = (const float*)d_in[2];
  const float* ln1_b = (const float*)d_in[3];
  const float* ln2_g = (const float*)d_in[4];
  const float* ln2_b = (const float*)d_in[5];
  const float* qk_w  = (const float*)d_in[6];
  const float* v_w   = (const float*)d_in[7];
  const float* v_b   = (const float*)d_in[8];
  const float* t1_w  = (const float*)d_in[9];
  const float* t1_b  = (const float*)d_in[10];
  const float* t2_w  = (const float*)d_in[11];
  const float* t2_b  = (const float*)d_in[12];
  const float* m1_w  = (const float*)d_in[13];
  const float* m1_b  = (const float*)d_in[14];
  const float* m2_w  = (const float*)d_in[15];
  const float* m2_b  = (const float*)d_in[16];

  char* ws = (char*)d_ws;
  float*          hf   = (float*)(ws + 0);                    // 134 MB (reused as x1)
  unsigned short* hbf  = (unsigned short*)(ws + 134217728);   // 67 MB  (reused as g)
  float*          Qt   = (float*)(ws + 201326592);            // 33.5 MB
  float*          part = (float*)(ws + 234881024);            // 16.8 MB
  float*          en   = (float*)(ws + 251658240);            // 2.1 MB
  float*          G    = (float*)(ws + 253755392);            // 8.4 MB
  float*          a2   = (float*)(ws + 262144000);            // 33.5 MB
  unsigned short* attT = (unsigned short*)(ws + 295698432);   // 16.8 MB
  unsigned short* xv   = (unsigned short*)(ws + 312475648);   // 67 MB
  unsigned short* h2   = (unsigned short*)(ws + 379584512);   // 67 MB
  unsigned short* wv   = (unsigned short*)(ws + 446693376);   // 2 MB
  unsigned short* wm1  = (unsigned short*)(ws + 448790528);   // 2 MB
  unsigned short* wm2  = (unsigned short*)(ws + 450887680);   // 2 MB  (total ~453 MB)
  float* x1 = hf;             // hf dead after Qt gemm
  unsigned short* gb = hbf;   // hbf dead after xv gemm
  float* out = (float*)d_out;

  // weights -> bf16
  cvt_bf16_kernel<<<dim3(1024), dim3(256), 0, stream>>>(v_w, wv, 262144);
  cvt_bf16_kernel<<<dim3(1024), dim3(256), 0, stream>>>(m1_w, wm1, 262144);
  cvt_bf16_kernel<<<dim3(1024), dim3(256), 0, stream>>>(m2_w, wm2, 262144);
  // h = LN1(x): f32 + bf16
  ln_kernel<<<dim3(32768), dim3(256), 0, stream>>>(x, ln1_g, ln1_b, hf, hbf);
  // Qt[b](256x4096) = qk_w(256x1024) @ h[b]^T
  gemm_f32<0><<<dim3(32, 2, 8), dim3(256), 0, stream>>>(
      qk_w, hf, Qt, nullptr, 1024, 1024, 1024, 4096, 0, 4194304, 1048576, 1);
  // xv(32768x1024,bf16) = hbf @ wv^T + v_b
  gemm_bf16<0><<<dim3(8, 256, 1), dim3(256), 0, stream>>>(
      hbf, wv, xv, v_b, nullptr, 1024, 1024, 1024, 1024, 0, 0, 0, 0);
  // energy partials: part[b*8+s](256x256) = Qt[b] @ Qt[b]^T over k-chunk s
  gemm_f32<0><<<dim3(2, 2, 64), dim3(256), 0, stream>>>(
      Qt, Qt, part, nullptr, 4096, 4096, 4096, 256, 1048576, 1048576, 65536, 8);
  ereduce_kernel<<<dim3(2048), dim3(256), 0, stream>>>(part, en);
  // G[b](1024x256) = gelu(t1_w @ en[b] + t1_b)   (en symmetric -> NT form)
  gemm_f32<1><<<dim3(2, 8, 8), dim3(256), 0, stream>>>(
      t1_w, en, G, t1_b, 256, 256, 256, 256, 0, 65536, 262144, 1);
  // a2[b](1024x1024) = t2_w @ G[b]^T + t2_b
  gemm_f32<2><<<dim3(8, 8, 8), dim3(256), 0, stream>>>(
      t2_w, G, a2, t2_b, 256, 256, 256, 1024, 0, 262144, 1048576, 1);
  // attT[b] = softmax(a2[b], axis=-1)^T  (bf16)
  smax_t_kernel<<<dim3(128, 8), dim3(256), 0, stream>>>(a2, attT);
  // x1[b](4096x1024,f32) = xv[b] @ attT[b]^T + x[b]
  gemm_bf16<2><<<dim3(8, 32, 8), dim3(256), 0, stream>>>(
      xv, attT, x1, nullptr, x, 1024, 1024, 1024, 1024, 4194304, 1048576, 4194304, 4194304);
  // h2 = LN2(x1) (bf16 only)
  ln_kernel<<<dim3(32768), dim3(256), 0, stream>>>(x1, ln2_g, ln2_b, nullptr, h2);
  // g = gelu(h2 @ wm1^T + m1_b) (bf16)
  gemm_bf16<1><<<dim3(8, 256, 1), dim3(256), 0, stream>>>(
      h2, wm1, gb, m1_b, nullptr, 1024, 1024, 1024, 1024, 0, 0, 0, 0);
  // out = x1 + g @ wm2^T + m2_b (f32)
  gemm_bf16<3><<<dim3(8, 256, 1), dim3(256), 0, stream>>>(
      gb, wm2, out, m2_b, x1, 1024, 1024, 1024, 1024, 0, 0, 0, 0);
}

// Round 3
// 757.849 us; speedup vs baseline: 1.3598x; 1.3598x over previous
//
#include <hip/hip_runtime.h>

// ---------------------------------------------------------------------------
// Enhanced_transformer  B=8, N=4096, P=1024, P4=256  (all fp32 in/out)
//
// All GEMMs on MFMA f16. Logit path (Qt, energy, G, a2) uses fp16-SPLIT
// (Markidis: x = hi + lo, C += hi*hi + hi*lo + lo*hi, f32 accum) for ~2^-22
// relative precision -- softmax logits have sigma~190, plain f16 would fail.
// Value/MLP path (xv, x1, m1, m2) uses plain f16 (5e-4 rel, linear impact).
// ---------------------------------------------------------------------------

typedef __attribute__((ext_vector_type(4))) float f32x4;
typedef __attribute__((ext_vector_type(8))) _Float16 h16x8;
typedef __attribute__((ext_vector_type(8))) unsigned short u16x8;
typedef __attribute__((ext_vector_type(4))) unsigned short u16x4;

__device__ __forceinline__ unsigned short f2h(float f) {
  _Float16 h = (_Float16)f;
  return __builtin_bit_cast(unsigned short, h);
}
// returns hi in bits[15:0], lo in bits[31:16]
__device__ __forceinline__ unsigned split16(float f) {
  _Float16 h = (_Float16)f;
  _Float16 l = (_Float16)(f - (float)h);
  return (unsigned)__builtin_bit_cast(unsigned short, h) |
         ((unsigned)__builtin_bit_cast(unsigned short, l) << 16);
}
__device__ __forceinline__ float gelu_f(float x) {
  return 0.5f * x * (1.0f + erff(x * 0.70710678118654752f));
}
__device__ __forceinline__ void gload16(const void* g, void* l) {
  __builtin_amdgcn_global_load_lds(
      (const __attribute__((address_space(1))) unsigned int*)g,
      (__attribute__((address_space(3))) unsigned int*)l, 16, 0, 0);
}

// ---------------- LayerNorm: row of 1024, out = f16 hi (+ optional lo) -----
__global__ __launch_bounds__(256)
void ln_kernel(const float* __restrict__ x, const float* __restrict__ g,
               const float* __restrict__ b, unsigned short* __restrict__ hi,
               unsigned short* __restrict__ lo) {
  __shared__ float red[16];
  const size_t base = (size_t)blockIdx.x * 1024;
  const int t = threadIdx.x;
  f32x4 v = *(const f32x4*)&x[base + t * 4];
  float s = v[0] + v[1] + v[2] + v[3];
  float q = v[0] * v[0] + v[1] * v[1] + v[2] * v[2] + v[3] * v[3];
#pragma unroll
  for (int o = 32; o > 0; o >>= 1) { s += __shfl_down(s, o); q += __shfl_down(q, o); }
  const int w = t >> 6;
  if ((t & 63) == 0) { red[w] = s; red[8 + w] = q; }
  __syncthreads();
  s = (red[0] + red[1]) + (red[2] + red[3]);
  q = (red[8] + red[9]) + (red[10] + red[11]);
  const float mu = s * (1.0f / 1024.0f);
  const float var = q * (1.0f / 1024.0f) - mu * mu;
  const float is = rsqrtf(var + 1e-5f);
  f32x4 gg = *(const f32x4*)&g[t * 4];
  f32x4 bb = *(const f32x4*)&b[t * 4];
  u16x4 oh, ol;
#pragma unroll
  for (int j = 0; j < 4; j++) {
    float y = (v[j] - mu) * is * gg[j] + bb[j];
    unsigned p = split16(y);
    oh[j] = (unsigned short)(p & 0xffffu);
    ol[j] = (unsigned short)(p >> 16);
  }
  *(u16x4*)&hi[base + t * 4] = oh;
  if (lo) *(u16x4*)&lo[base + t * 4] = ol;
}

// ---------------- fp32 -> f16 (hi + optional lo) ---------------------------
__global__ __launch_bounds__(256)
void cvt_kernel(const float* __restrict__ in, unsigned short* __restrict__ hi,
                unsigned short* __restrict__ lo, int n4) {
  int i = blockIdx.x * 256 + threadIdx.x;
  if (i < n4) {
    f32x4 v = *(const f32x4*)&in[(size_t)i * 4];
    u16x4 oh, ol;
#pragma unroll
    for (int j = 0; j < 4; j++) {
      unsigned p = split16(v[j]);
      oh[j] = (unsigned short)(p & 0xffffu);
      ol[j] = (unsigned short)(p >> 16);
    }
    *(u16x4*)&hi[(size_t)i * 4] = oh;
    if (lo) *(u16x4*)&lo[(size_t)i * 4] = ol;
  }
}

// ---------------- f16 MFMA GEMM: C = A(MxK) * B(NxK)^T ---------------------
// 128x128 tile, BK=64, 4 waves each 64x64 (4x4 frags of 16x16x32_f16).
// SPLIT=1: A/B given as hi/lo planes, 3 MFMAs per frag-pair (f32 accum).
// EPI: 0 f16 out +bias[col]           (xv)
//      1 f16 out +bias[col] +gelu     (m1)
//      2 f32 out +res                 (x1)
//      3 f32 out +bias[col] +res      (m2 -> d_out)
//      4 f16 hi/lo out                (Qt)
//      5 f32 out                      (energy partials)
//      6 f16 hi/lo out +bias[row] +gelu (G)
//      7 f32 out +bias[row]           (a2)
template <int EPI, int SPLIT>
__global__ __launch_bounds__(256)
void gemm16(const unsigned short* __restrict__ Ahi, const unsigned short* __restrict__ Alo,
            const unsigned short* __restrict__ Bhi, const unsigned short* __restrict__ Blo,
            void* __restrict__ Cout, unsigned short* __restrict__ Cout2,
            const float* __restrict__ bias, const float* __restrict__ resIn,
            int K, int lda, int ldb, int ldc,
            long long sA, long long sB, long long sC, long long sRes, int splitK) {
  __shared__ short As[(1 + SPLIT) * 128 * 64];
  __shared__ short Bs[(1 + SPLIT) * 128 * 64];
  const int z = blockIdx.z;
  const int bi = z / splitK, sp = z % splitK;
  const int kLen = K / splitK, kStart = sp * kLen;
  const unsigned short* AH = Ahi + (size_t)bi * sA;
  const unsigned short* BH = Bhi + (size_t)bi * sB;
  const unsigned short* AL = SPLIT ? Alo + (size_t)bi * sA : nullptr;
  const unsigned short* BL = SPLIT ? Blo + (size_t)bi * sB : nullptr;
  const int mBase = blockIdx.y * 128, nBase = blockIdx.x * 128;
  const int t = threadIdx.x, w = t >> 6, l = t & 63;
  const int r16 = l & 15, kq = l >> 4;
  const int wr = (w >> 1) * 64, wc = (w & 1) * 64;
  f32x4 acc[4][4] = {};

  for (int k0 = kStart; k0 < kStart + kLen; k0 += 64) {
#pragma unroll
    for (int it = 0; it < 4; ++it) {
      const int c = it * 256 + t;              // chunk id (8 f16 each)
      const int row = c >> 3, cc = c & 7;
      const int gc = cc ^ (row & 7);           // source-side swizzle
      const int cbase = it * 256 + w * 64;     // wave-uniform LDS base chunk
      const size_t ga = (size_t)(mBase + row) * lda + k0 + gc * 8;
      const size_t gb = (size_t)(nBase + row) * ldb + k0 + gc * 8;
      gload16(&AH[ga], &As[cbase * 8]);
      gload16(&BH[gb], &Bs[cbase * 8]);
      if constexpr (SPLIT) {
        gload16(&AL[ga], &As[8192 + cbase * 8]);
        gload16(&BL[gb], &Bs[8192 + cbase * 8]);
      }
    }
    asm volatile("s_waitcnt vmcnt(0)" ::: "memory");
    __syncthreads();
#pragma unroll
    for (int kk = 0; kk < 2; ++kk) {
      h16x8 aH[4], bH[4], aL[4], bL[4];
#pragma unroll
      for (int mi = 0; mi < 4; mi++) {
        const int r = wr + mi * 16 + r16;
        const int cc = (kk * 4 + kq) ^ (r & 7);  // read-side swizzle
        aH[mi] = *(const h16x8*)&As[r * 64 + cc * 8];
        if constexpr (SPLIT) aL[mi] = *(const h16x8*)&As[8192 + r * 64 + cc * 8];
      }
#pragma unroll
      for (int ni = 0; ni < 4; ni++) {
        const int r = wc + ni * 16 + r16;
        const int cc = (kk * 4 + kq) ^ (r & 7);
        bH[ni] = *(const h16x8*)&Bs[r * 64 + cc * 8];
        if constexpr (SPLIT) bL[ni] = *(const h16x8*)&Bs[8192 + r * 64 + cc * 8];
      }
#pragma unroll
      for (int mi = 0; mi < 4; mi++)
#pragma unroll
        for (int ni = 0; ni < 4; ni++) {
          acc[mi][ni] = __builtin_amdgcn_mfma_f32_16x16x32_f16(aH[mi], bH[ni], acc[mi][ni], 0, 0, 0);
          if constexpr (SPLIT) {
            acc[mi][ni] = __builtin_amdgcn_mfma_f32_16x16x32_f16(aH[mi], bL[ni], acc[mi][ni], 0, 0, 0);
            acc[mi][ni] = __builtin_amdgcn_mfma_f32_16x16x32_f16(aL[mi], bH[ni], acc[mi][ni], 0, 0, 0);
          }
        }
    }
    __syncthreads();
  }

  unsigned short* C16 = (unsigned short*)Cout + (size_t)z * sC;
  unsigned short* C16b = Cout2 ? Cout2 + (size_t)z * sC : nullptr;
  float* C32 = (float*)Cout + (size_t)z * sC;
  const float* res = (EPI == 2 || EPI == 3) ? (resIn + (size_t)z * sRes) : nullptr;
#pragma unroll
  for (int mi = 0; mi < 4; mi++) {
#pragma unroll
    for (int ni = 0; ni < 4; ni++) {
      const int cl = nBase + wc + ni * 16 + r16;
      float bcol = 0.0f;
      if (EPI == 0 || EPI == 1 || EPI == 3) bcol = bias[cl];
#pragma unroll
      for (int r = 0; r < 4; r++) {
        const int rw = mBase + wr + mi * 16 + kq * 4 + r;   // C/D: row=(l>>4)*4+r, col=l&15
        float v = acc[mi][ni][r] + bcol;
        if (EPI == 6 || EPI == 7) v += bias[rw];
        if (EPI == 1 || EPI == 6) v = gelu_f(v);
        if (EPI == 2 || EPI == 3) v += res[(size_t)rw * ldc + cl];
        const size_t idx = (size_t)rw * ldc + cl;
        if (EPI == 0 || EPI == 1) C16[idx] = f2h(v);
        else if (EPI == 4 || EPI == 6) {
          unsigned p = split16(v);
          C16[idx] = (unsigned short)(p & 0xffffu);
          C16b[idx] = (unsigned short)(p >> 16);
        }
        else C32[idx] = v;
      }
    }
  }
}

// ---------------- energy split-K reduce -> f16 hi/lo -----------------------
__global__ __launch_bounds__(256)
void ereduce_kernel(const float* __restrict__ part, unsigned short* __restrict__ ehi,
                    unsigned short* __restrict__ elo) {
  const size_t idx = (size_t)blockIdx.x * 256 + threadIdx.x;  // 8*65536 total
  const size_t b = idx >> 16, i = idx & 65535;
  const float* p = part + b * (8ull * 65536) + i;
  float s0 = (p[0] + p[65536]) + (p[2 * 65536] + p[3 * 65536]);
  float s1 = (p[4 * 65536] + p[5 * 65536]) + (p[6 * 65536] + p[7 * 65536]);
  unsigned pk = split16(s0 + s1);
  ehi[idx] = (unsigned short)(pk & 0xffffu);
  elo[idx] = (unsigned short)(pk >> 16);
}

// ---------------- softmax over rows + transpose -> f16 ---------------------
__global__ __launch_bounds__(256)
void smax_t_kernel(const float* __restrict__ a2, unsigned short* __restrict__ attT) {
  __shared__ float S[8][1028];
  __shared__ float inv[8];
  const int t = threadIdx.x;
  const int b = blockIdx.y;
  const int o0 = blockIdx.x * 8;
  const float* src = a2 + ((size_t)b * 1024 + o0) * 1024;
#pragma unroll
  for (int i = 0; i < 8; i++)
    *(f32x4*)&S[i][t * 4] = *(const f32x4*)&src[(size_t)i * 1024 + t * 4];
  __syncthreads();
  const int w = t >> 6, l = t & 63;
  for (int rr = 0; rr < 2; rr++) {
    const int r = w * 2 + rr;
    float m = -1e30f;
#pragma unroll
    for (int i = 0; i < 16; i++) m = fmaxf(m, S[r][l + i * 64]);
#pragma unroll
    for (int o = 32; o > 0; o >>= 1) m = fmaxf(m, __shfl_xor(m, o));
    float ssum = 0.0f;
#pragma unroll
    for (int i = 0; i < 16; i++) {
      float e = expf(S[r][l + i * 64] - m);
      S[r][l + i * 64] = e;
      ssum += e;
    }
#pragma unroll
    for (int o = 32; o > 0; o >>= 1) ssum += __shfl_xor(ssum, o);
    if (l == 0) inv[r] = 1.0f / ssum;
  }
  __syncthreads();
  float iv[8];
#pragma unroll
  for (int r = 0; r < 8; r++) iv[r] = inv[r];
#pragma unroll
  for (int i = 0; i < 4; i++) {
    const int k = i * 256 + t;
    u16x8 ov;
#pragma unroll
    for (int r = 0; r < 8; r++) ov[r] = f2h(S[r][k] * iv[r]);
    *(u16x8*)&attT[((size_t)b * 1024 + k) * 1024 + o0] = ov;
  }
}

// ---------------------------------------------------------------------------
extern "C" void kernel_launch(void* const* d_in, const int* in_sizes, int n_in,
                              void* d_out, int out_size, void* d_ws, size_t ws_size,
                              hipStream_t stream) {
  (void)in_sizes; (void)n_in; (void)out_size; (void)ws_size;
  const float* x     = (const float*)d_in[1];
  const float* ln1_g = (const float*)d_in[2];
  const float* ln1_b = (const float*)d_in[3];
  const float* ln2_g = (const float*)d_in[4];
  const float* ln2_b = (const float*)d_in[5];
  const float* qk_w  = (const float*)d_in[6];
  const float* v_w   = (const float*)d_in[7];
  const float* v_b   = (const float*)d_in[8];
  const float* t1_w  = (const float*)d_in[9];
  const float* t1_b  = (const float*)d_in[10];
  const float* t2_w  = (const float*)d_in[11];
  const float* t2_b  = (const float*)d_in[12];
  const float* m1_w  = (const float*)d_in[13];
  const float* m1_b  = (const float*)d_in[14];
  const float* m2_w  = (const float*)d_in[15];
  const float* m2_b  = (const float*)d_in[16];

  char* ws = (char*)d_ws;
  unsigned short* hhi  = (unsigned short*)(ws + 0);            // 67 MB (-> h2)
  unsigned short* hlo  = (unsigned short*)(ws + 67108864);     // 67 MB (-> g)
  unsigned short* Qthi = (unsigned short*)(ws + 134217728);    // 16.8 MB
  unsigned short* Qtlo = (unsigned short*)(ws + 150994944);    // 16.8 MB
  float*          part = (float*)(ws + 167772160);             // 16.8 MB
  unsigned short* Ehi  = (unsigned short*)(ws + 184549376);    // 1 MB
  unsigned short* Elo  = (unsigned short*)(ws + 185597952);    // 1 MB
  unsigned short* Ghi  = (unsigned short*)(ws + 186646528);    // 4.2 MB
  unsigned short* Glo  = (unsigned short*)(ws + 190840832);    // 4.2 MB
  float*          a2   = (float*)(ws + 195035136);             // 33.5 MB
  unsigned short* attT = (unsigned short*)(ws + 228589568);    // 16.8 MB
  unsigned short* xv   = (unsigned short*)(ws + 245366784);    // 67 MB
  float*          x1   = (float*)(ws + 312475648);             // 134 MB
  unsigned short* wqh  = (unsigned short*)(ws + 446693376);    // 0.5 MB
  unsigned short* wql  = (unsigned short*)(ws + 447217664);
  unsigned short* wv   = (unsigned short*)(ws + 447741952);    // 2 MB
  unsigned short* wt1h = (unsigned short*)(ws + 449839104);
  unsigned short* wt1l = (unsigned short*)(ws + 450363392);
  unsigned short* wt2h = (unsigned short*)(ws + 450887680);
  unsigned short* wt2l = (unsigned short*)(ws + 451411968);
  unsigned short* wm1  = (unsigned short*)(ws + 451936256);    // 2 MB
  unsigned short* wm2  = (unsigned short*)(ws + 454033408);    // 2 MB (total ~456 MB)
  unsigned short* h2 = hhi;   // dead after xv gemm
  unsigned short* gb = hlo;   // dead after Qt gemm
  float* out = (float*)d_out;

  // weight converts
  cvt_kernel<<<dim3(256),  dim3(256), 0, stream>>>(qk_w, wqh, wql, 65536);
  cvt_kernel<<<dim3(1024), dim3(256), 0, stream>>>(v_w, wv, nullptr, 262144);
  cvt_kernel<<<dim3(256),  dim3(256), 0, stream>>>(t1_w, wt1h, wt1l, 65536);
  cvt_kernel<<<dim3(256),  dim3(256), 0, stream>>>(t2_w, wt2h, wt2l, 65536);
  cvt_kernel<<<dim3(1024), dim3(256), 0, stream>>>(m1_w, wm1, nullptr, 262144);
  cvt_kernel<<<dim3(1024), dim3(256), 0, stream>>>(m2_w, wm2, nullptr, 262144);
  // h = LN1(x) -> hi/lo
  ln_kernel<<<dim3(32768), dim3(256), 0, stream>>>(x, ln1_g, ln1_b, hhi, hlo);
  // Qt[b](256x4096) = qk_w @ h[b]^T   (split, hi/lo out)
  gemm16<4, 1><<<dim3(32, 2, 8), dim3(256), 0, stream>>>(
      wqh, wql, hhi, hlo, Qthi, Qtlo, nullptr, nullptr,
      1024, 1024, 1024, 4096, 0, 4194304, 1048576, 0, 1);
  // xv(32768x1024) = h @ v_w^T + v_b  (f16)
  gemm16<0, 0><<<dim3(8, 256, 1), dim3(256), 0, stream>>>(
      hhi, nullptr, wv, nullptr, xv, nullptr, v_b, nullptr,
      1024, 1024, 1024, 1024, 0, 0, 0, 0, 1);
  // energy partials: part[b*8+s](256x256) = Qt[b] @ Qt[b]^T over k-chunk s
  gemm16<5, 1><<<dim3(2, 2, 64), dim3(256), 0, stream>>>(
      Qthi, Qtlo, Qthi, Qtlo, part, nullptr, nullptr, nullptr,
      4096, 4096, 4096, 256, 1048576, 1048576, 65536, 0, 8);
  ereduce_kernel<<<dim3(2048), dim3(256), 0, stream>>>(part, Ehi, Elo);
  // G[b](1024x256) = gelu(t1_w @ en[b] + t1_b)  (en symmetric -> NT; split out)
  gemm16<6, 1><<<dim3(2, 8, 8), dim3(256), 0, stream>>>(
      wt1h, wt1l, Ehi, Elo, Ghi, Glo, t1_b, nullptr,
      256, 256, 256, 256, 0, 65536, 262144, 0, 1);
  // a2[b](1024x1024) = t2_w @ G[b]^T + t2_b  (f32 out)
  gemm16<7, 1><<<dim3(8, 8, 8), dim3(256), 0, stream>>>(
      wt2h, wt2l, Ghi, Glo, a2, nullptr, t2_b, nullptr,
      256, 256, 256, 1024, 0, 262144, 1048576, 0, 1);
  // attT[b] = softmax(a2[b], -1)^T  (f16)
  smax_t_kernel<<<dim3(128, 8), dim3(256), 0, stream>>>(a2, attT);
  // x1[b](4096x1024,f32) = xv[b] @ attT[b]^T + x[b]
  gemm16<2, 0><<<dim3(8, 32, 8), dim3(256), 0, stream>>>(
      xv, nullptr, attT, nullptr, x1, nullptr, nullptr, x,
      1024, 1024, 1024, 1024, 4194304, 1048576, 4194304, 4194304, 1);
  // h2 = LN2(x1) (f16 hi only)
  ln_kernel<<<dim3(32768), dim3(256), 0, stream>>>(x1, ln2_g, ln2_b, h2, nullptr);
  // g = gelu(h2 @ m1_w^T + m1_b)
  gemm16<1, 0><<<dim3(8, 256, 1), dim3(256), 0, stream>>>(
      h2, nullptr, wm1, nullptr, gb, nullptr, m1_b, nullptr,
      1024, 1024, 1024, 1024, 0, 0, 0, 0, 1);
  // out = x1 + g @ m2_w^T + m2_b (f32)
  gemm16<3, 0><<<dim3(8, 256, 1), dim3(256), 0, stream>>>(
      gb, nullptr, wm2, nullptr, out, nullptr, m2_b, x1,
      1024, 1024, 1024, 1024, 0, 0, 0, 0, 1);
}

// Round 4
// 733.546 us; speedup vs baseline: 1.4048x; 1.0331x over previous
//
#include <hip/hip_runtime.h>

// ---------------------------------------------------------------------------
// Enhanced_transformer  B=8, N=4096, P=1024, P4=256  (all fp32 in/out)
//
// All GEMMs on MFMA f16. Logit path (Qt, energy, G, a2) uses fp16-SPLIT
// (Markidis: x = hi + lo, C += hi*hi + hi*lo + lo*hi, f32 accum) for ~2^-22
// relative precision -- softmax logits have sigma~190, plain f16 would fail.
// Value/MLP path (xv, x1, m1, m2) uses plain f16 (5e-4 rel, linear impact).
// R4: non-split GEMMs get double-buffered LDS with STAGE-before-compute
// (T3-lite 2-phase) + bijective XCD chunk-swizzle on tile ids (T1).
// ---------------------------------------------------------------------------

typedef __attribute__((ext_vector_type(4))) float f32x4;
typedef __attribute__((ext_vector_type(8))) _Float16 h16x8;
typedef __attribute__((ext_vector_type(8))) unsigned short u16x8;
typedef __attribute__((ext_vector_type(4))) unsigned short u16x4;

__device__ __forceinline__ unsigned short f2h(float f) {
  _Float16 h = (_Float16)f;
  return __builtin_bit_cast(unsigned short, h);
}
// returns hi in bits[15:0], lo in bits[31:16]
__device__ __forceinline__ unsigned split16(float f) {
  _Float16 h = (_Float16)f;
  _Float16 l = (_Float16)(f - (float)h);
  return (unsigned)__builtin_bit_cast(unsigned short, h) |
         ((unsigned)__builtin_bit_cast(unsigned short, l) << 16);
}
__device__ __forceinline__ float gelu_f(float x) {
  return 0.5f * x * (1.0f + erff(x * 0.70710678118654752f));
}
__device__ __forceinline__ void gload16(const void* g, void* l) {
  __builtin_amdgcn_global_load_lds(
      (const __attribute__((address_space(1))) unsigned int*)g,
      (__attribute__((address_space(3))) unsigned int*)l, 16, 0, 0);
}

// ---------------- LayerNorm: row of 1024, out = f16 hi (+ optional lo) -----
__global__ __launch_bounds__(256)
void ln_kernel(const float* __restrict__ x, const float* __restrict__ g,
               const float* __restrict__ b, unsigned short* __restrict__ hi,
               unsigned short* __restrict__ lo) {
  __shared__ float red[16];
  const size_t base = (size_t)blockIdx.x * 1024;
  const int t = threadIdx.x;
  f32x4 v = *(const f32x4*)&x[base + t * 4];
  float s = v[0] + v[1] + v[2] + v[3];
  float q = v[0] * v[0] + v[1] * v[1] + v[2] * v[2] + v[3] * v[3];
#pragma unroll
  for (int o = 32; o > 0; o >>= 1) { s += __shfl_down(s, o); q += __shfl_down(q, o); }
  const int w = t >> 6;
  if ((t & 63) == 0) { red[w] = s; red[8 + w] = q; }
  __syncthreads();
  s = (red[0] + red[1]) + (red[2] + red[3]);
  q = (red[8] + red[9]) + (red[10] + red[11]);
  const float mu = s * (1.0f / 1024.0f);
  const float var = q * (1.0f / 1024.0f) - mu * mu;
  const float is = rsqrtf(var + 1e-5f);
  f32x4 gg = *(const f32x4*)&g[t * 4];
  f32x4 bb = *(const f32x4*)&b[t * 4];
  u16x4 oh, ol;
#pragma unroll
  for (int j = 0; j < 4; j++) {
    float y = (v[j] - mu) * is * gg[j] + bb[j];
    unsigned p = split16(y);
    oh[j] = (unsigned short)(p & 0xffffu);
    ol[j] = (unsigned short)(p >> 16);
  }
  *(u16x4*)&hi[base + t * 4] = oh;
  if (lo) *(u16x4*)&lo[base + t * 4] = ol;
}

// ---------------- fp32 -> f16 (hi + optional lo) ---------------------------
__global__ __launch_bounds__(256)
void cvt_kernel(const float* __restrict__ in, unsigned short* __restrict__ hi,
                unsigned short* __restrict__ lo, int n4) {
  int i = blockIdx.x * 256 + threadIdx.x;
  if (i < n4) {
    f32x4 v = *(const f32x4*)&in[(size_t)i * 4];
    u16x4 oh, ol;
#pragma unroll
    for (int j = 0; j < 4; j++) {
      unsigned p = split16(v[j]);
      oh[j] = (unsigned short)(p & 0xffffu);
      ol[j] = (unsigned short)(p >> 16);
    }
    *(u16x4*)&hi[(size_t)i * 4] = oh;
    if (lo) *(u16x4*)&lo[(size_t)i * 4] = ol;
  }
}

// ---------------- f16 MFMA GEMM: C = A(MxK) * B(NxK)^T ---------------------
// 128x128 tile, BK=64, 4 waves each 64x64 (4x4 frags of 16x16x32_f16).
// SPLIT=1: A/B as hi/lo planes, 3 MFMAs per frag-pair, single-buffer serial.
// SPLIT=0: double-buffered LDS, STAGE(t+1) issued before compute(t).
// EPI: 0 f16 out +bias[col]           (xv)
//      1 f16 out +bias[col] +gelu     (m1)
//      2 f32 out +res                 (x1)
//      3 f32 out +bias[col] +res      (m2 -> d_out)
//      4 f16 hi/lo out                (Qt)
//      5 f32 out                      (energy partials)
//      6 f16 hi/lo out +bias[row] +gelu (G)
//      7 f32 out +bias[row]           (a2)
template <int EPI, int SPLIT>
__global__ __launch_bounds__(256)
void gemm16(const unsigned short* __restrict__ Ahi, const unsigned short* __restrict__ Alo,
            const unsigned short* __restrict__ Bhi, const unsigned short* __restrict__ Blo,
            void* __restrict__ Cout, unsigned short* __restrict__ Cout2,
            const float* __restrict__ bias, const float* __restrict__ resIn,
            int K, int lda, int ldb, int ldc,
            long long sA, long long sB, long long sC, long long sRes, int splitK) {
  // [2][8192]: SPLIT=1 -> hi/lo planes; SPLIT=0 -> double buffer.
  __shared__ short As[16384];
  __shared__ short Bs[16384];
  const int z = blockIdx.z;
  const int bi = z / splitK, sp = z % splitK;
  const int kLen = K / splitK, kStart = sp * kLen;
  const unsigned short* AH = Ahi + (size_t)bi * sA;
  const unsigned short* BH = Bhi + (size_t)bi * sB;
  const unsigned short* AL = SPLIT ? Alo + (size_t)bi * sA : nullptr;
  const unsigned short* BL = SPLIT ? Blo + (size_t)bi * sB : nullptr;

  // bijective XCD chunk-swizzle (T1): give each XCD a contiguous tile range
  int bx = blockIdx.x, by = blockIdx.y;
  {
    const int nwg = gridDim.x * gridDim.y;
    if ((nwg & 7) == 0 && nwg >= 16) {
      const int flat = bx + gridDim.x * by;
      const int chunk = nwg >> 3;
      const int nf = (flat & 7) * chunk + (flat >> 3);
      bx = nf % gridDim.x;
      by = nf / gridDim.x;
    }
  }
  const int mBase = by * 128, nBase = bx * 128;
  const int t = threadIdx.x, w = t >> 6, l = t & 63;
  const int r16 = l & 15, kq = l >> 4;
  const int wr = (w >> 1) * 64, wc = (w & 1) * 64;
  f32x4 acc[4][4] = {};

  // stage one 128x64 A-tile + B-tile (hi planes) into buffer `buf`
  auto stage_hi = [&](int buf, int k0) {
#pragma unroll
    for (int it = 0; it < 4; ++it) {
      const int c = it * 256 + t;              // chunk id (8 f16 each)
      const int row = c >> 3, cc = c & 7;
      const int gc = cc ^ (row & 7);           // source-side swizzle
      const int cbase = it * 256 + w * 64;     // wave-uniform LDS base chunk
      gload16(&AH[(size_t)(mBase + row) * lda + k0 + gc * 8], &As[buf * 8192 + cbase * 8]);
      gload16(&BH[(size_t)(nBase + row) * ldb + k0 + gc * 8], &Bs[buf * 8192 + cbase * 8]);
    }
  };

  if constexpr (!SPLIT) {
    const int nt = kLen >> 6;
    stage_hi(0, kStart);
    asm volatile("s_waitcnt vmcnt(0)" ::: "memory");
    __syncthreads();
    int cur = 0;
    for (int ts = 0; ts < nt; ++ts) {
      if (ts + 1 < nt) stage_hi(cur ^ 1, kStart + (ts + 1) * 64);
#pragma unroll
      for (int kk = 0; kk < 2; ++kk) {
        h16x8 aH[4], bH[4];
#pragma unroll
        for (int mi = 0; mi < 4; mi++) {
          const int r = wr + mi * 16 + r16;
          const int cc = (kk * 4 + kq) ^ (r & 7);
          aH[mi] = *(const h16x8*)&As[cur * 8192 + r * 64 + cc * 8];
        }
#pragma unroll
        for (int ni = 0; ni < 4; ni++) {
          const int r = wc + ni * 16 + r16;
          const int cc = (kk * 4 + kq) ^ (r & 7);
          bH[ni] = *(const h16x8*)&Bs[cur * 8192 + r * 64 + cc * 8];
        }
#pragma unroll
        for (int mi = 0; mi < 4; mi++)
#pragma unroll
          for (int ni = 0; ni < 4; ni++)
            acc[mi][ni] = __builtin_amdgcn_mfma_f32_16x16x32_f16(aH[mi], bH[ni], acc[mi][ni], 0, 0, 0);
      }
      asm volatile("s_waitcnt vmcnt(0)" ::: "memory");
      __syncthreads();
      cur ^= 1;
    }
  } else {
    for (int k0 = kStart; k0 < kStart + kLen; k0 += 64) {
#pragma unroll
      for (int it = 0; it < 4; ++it) {
        const int c = it * 256 + t;
        const int row = c >> 3, cc = c & 7;
        const int gc = cc ^ (row & 7);
        const int cbase = it * 256 + w * 64;
        const size_t ga = (size_t)(mBase + row) * lda + k0 + gc * 8;
        const size_t gb = (size_t)(nBase + row) * ldb + k0 + gc * 8;
        gload16(&AH[ga], &As[cbase * 8]);
        gload16(&BH[gb], &Bs[cbase * 8]);
        gload16(&AL[ga], &As[8192 + cbase * 8]);
        gload16(&BL[gb], &Bs[8192 + cbase * 8]);
      }
      asm volatile("s_waitcnt vmcnt(0)" ::: "memory");
      __syncthreads();
#pragma unroll
      for (int kk = 0; kk < 2; ++kk) {
        h16x8 aH[4], bH[4], aL[4], bL[4];
#pragma unroll
        for (int mi = 0; mi < 4; mi++) {
          const int r = wr + mi * 16 + r16;
          const int cc = (kk * 4 + kq) ^ (r & 7);
          aH[mi] = *(const h16x8*)&As[r * 64 + cc * 8];
          aL[mi] = *(const h16x8*)&As[8192 + r * 64 + cc * 8];
        }
#pragma unroll
        for (int ni = 0; ni < 4; ni++) {
          const int r = wc + ni * 16 + r16;
          const int cc = (kk * 4 + kq) ^ (r & 7);
          bH[ni] = *(const h16x8*)&Bs[r * 64 + cc * 8];
          bL[ni] = *(const h16x8*)&Bs[8192 + r * 64 + cc * 8];
        }
#pragma unroll
        for (int mi = 0; mi < 4; mi++)
#pragma unroll
          for (int ni = 0; ni < 4; ni++) {
            acc[mi][ni] = __builtin_amdgcn_mfma_f32_16x16x32_f16(aH[mi], bH[ni], acc[mi][ni], 0, 0, 0);
            acc[mi][ni] = __builtin_amdgcn_mfma_f32_16x16x32_f16(aH[mi], bL[ni], acc[mi][ni], 0, 0, 0);
            acc[mi][ni] = __builtin_amdgcn_mfma_f32_16x16x32_f16(aL[mi], bH[ni], acc[mi][ni], 0, 0, 0);
          }
      }
      __syncthreads();
    }
  }

  unsigned short* C16 = (unsigned short*)Cout + (size_t)z * sC;
  unsigned short* C16b = Cout2 ? Cout2 + (size_t)z * sC : nullptr;
  float* C32 = (float*)Cout + (size_t)z * sC;
  const float* res = (EPI == 2 || EPI == 3) ? (resIn + (size_t)z * sRes) : nullptr;
#pragma unroll
  for (int mi = 0; mi < 4; mi++) {
#pragma unroll
    for (int ni = 0; ni < 4; ni++) {
      const int cl = nBase + wc + ni * 16 + r16;
      float bcol = 0.0f;
      if (EPI == 0 || EPI == 1 || EPI == 3) bcol = bias[cl];
#pragma unroll
      for (int r = 0; r < 4; r++) {
        const int rw = mBase + wr + mi * 16 + kq * 4 + r;   // C/D: row=(l>>4)*4+r, col=l&15
        float v = acc[mi][ni][r] + bcol;
        if (EPI == 6 || EPI == 7) v += bias[rw];
        if (EPI == 1 || EPI == 6) v = gelu_f(v);
        if (EPI == 2 || EPI == 3) v += res[(size_t)rw * ldc + cl];
        const size_t idx = (size_t)rw * ldc + cl;
        if (EPI == 0 || EPI == 1) C16[idx] = f2h(v);
        else if (EPI == 4 || EPI == 6) {
          unsigned p = split16(v);
          C16[idx] = (unsigned short)(p & 0xffffu);
          C16b[idx] = (unsigned short)(p >> 16);
        }
        else C32[idx] = v;
      }
    }
  }
}

// ---------------- energy split-K reduce -> f16 hi/lo -----------------------
__global__ __launch_bounds__(256)
void ereduce_kernel(const float* __restrict__ part, unsigned short* __restrict__ ehi,
                    unsigned short* __restrict__ elo) {
  const size_t idx = (size_t)blockIdx.x * 256 + threadIdx.x;  // 8*65536 total
  const size_t b = idx >> 16, i = idx & 65535;
  const float* p = part + b * (8ull * 65536) + i;
  float s0 = (p[0] + p[65536]) + (p[2 * 65536] + p[3 * 65536]);
  float s1 = (p[4 * 65536] + p[5 * 65536]) + (p[6 * 65536] + p[7 * 65536]);
  unsigned pk = split16(s0 + s1);
  ehi[idx] = (unsigned short)(pk & 0xffffu);
  elo[idx] = (unsigned short)(pk >> 16);
}

// ---------------- softmax over rows + transpose -> f16 ---------------------
__global__ __launch_bounds__(256)
void smax_t_kernel(const float* __restrict__ a2, unsigned short* __restrict__ attT) {
  __shared__ float S[8][1028];
  __shared__ float inv[8];
  const int t = threadIdx.x;
  const int b = blockIdx.y;
  const int o0 = blockIdx.x * 8;
  const float* src = a2 + ((size_t)b * 1024 + o0) * 1024;
#pragma unroll
  for (int i = 0; i < 8; i++)
    *(f32x4*)&S[i][t * 4] = *(const f32x4*)&src[(size_t)i * 1024 + t * 4];
  __syncthreads();
  const int w = t >> 6, l = t & 63;
  for (int rr = 0; rr < 2; rr++) {
    const int r = w * 2 + rr;
    float m = -1e30f;
#pragma unroll
    for (int i = 0; i < 16; i++) m = fmaxf(m, S[r][l + i * 64]);
#pragma unroll
    for (int o = 32; o > 0; o >>= 1) m = fmaxf(m, __shfl_xor(m, o));
    float ssum = 0.0f;
#pragma unroll
    for (int i = 0; i < 16; i++) {
      float e = expf(S[r][l + i * 64] - m);
      S[r][l + i * 64] = e;
      ssum += e;
    }
#pragma unroll
    for (int o = 32; o > 0; o >>= 1) ssum += __shfl_xor(ssum, o);
    if (l == 0) inv[r] = 1.0f / ssum;
  }
  __syncthreads();
  float iv[8];
#pragma unroll
  for (int r = 0; r < 8; r++) iv[r] = inv[r];
#pragma unroll
  for (int i = 0; i < 4; i++) {
    const int k = i * 256 + t;
    u16x8 ov;
#pragma unroll
    for (int r = 0; r < 8; r++) ov[r] = f2h(S[r][k] * iv[r]);
    *(u16x8*)&attT[((size_t)b * 1024 + k) * 1024 + o0] = ov;
  }
}

// ---------------------------------------------------------------------------
extern "C" void kernel_launch(void* const* d_in, const int* in_sizes, int n_in,
                              void* d_out, int out_size, void* d_ws, size_t ws_size,
                              hipStream_t stream) {
  (void)in_sizes; (void)n_in; (void)out_size; (void)ws_size;
  const float* x     = (const float*)d_in[1];
  const float* ln1_g = (const float*)d_in[2];
  const float* ln1_b = (const float*)d_in[3];
  const float* ln2_g = (const float*)d_in[4];
  const float* ln2_b = (const float*)d_in[5];
  const float* qk_w  = (const float*)d_in[6];
  const float* v_w   = (const float*)d_in[7];
  const float* v_b   = (const float*)d_in[8];
  const float* t1_w  = (const float*)d_in[9];
  const float* t1_b  = (const float*)d_in[10];
  const float* t2_w  = (const float*)d_in[11];
  const float* t2_b  = (const float*)d_in[12];
  const float* m1_w  = (const float*)d_in[13];
  const float* m1_b  = (const float*)d_in[14];
  const float* m2_w  = (const float*)d_in[15];
  const float* m2_b  = (const float*)d_in[16];

  char* ws = (char*)d_ws;
  unsigned short* hhi  = (unsigned short*)(ws + 0);            // 67 MB (-> h2)
  unsigned short* hlo  = (unsigned short*)(ws + 67108864);     // 67 MB (-> g)
  unsigned short* Qthi = (unsigned short*)(ws + 134217728);    // 16.8 MB
  unsigned short* Qtlo = (unsigned short*)(ws + 150994944);    // 16.8 MB
  float*          part = (float*)(ws + 167772160);             // 16.8 MB
  unsigned short* Ehi  = (unsigned short*)(ws + 184549376);    // 1 MB
  unsigned short* Elo  = (unsigned short*)(ws + 185597952);    // 1 MB
  unsigned short* Ghi  = (unsigned short*)(ws + 186646528);    // 4.2 MB
  unsigned short* Glo  = (unsigned short*)(ws + 190840832);    // 4.2 MB
  float*          a2   = (float*)(ws + 195035136);             // 33.5 MB
  unsigned short* attT = (unsigned short*)(ws + 228589568);    // 16.8 MB
  unsigned short* xv   = (unsigned short*)(ws + 245366784);    // 67 MB
  float*          x1   = (float*)(ws + 312475648);             // 134 MB
  unsigned short* wqh  = (unsigned short*)(ws + 446693376);    // 0.5 MB
  unsigned short* wql  = (unsigned short*)(ws + 447217664);
  unsigned short* wv   = (unsigned short*)(ws + 447741952);    // 2 MB
  unsigned short* wt1h = (unsigned short*)(ws + 449839104);
  unsigned short* wt1l = (unsigned short*)(ws + 450363392);
  unsigned short* wt2h = (unsigned short*)(ws + 450887680);
  unsigned short* wt2l = (unsigned short*)(ws + 451411968);
  unsigned short* wm1  = (unsigned short*)(ws + 451936256);    // 2 MB
  unsigned short* wm2  = (unsigned short*)(ws + 454033408);    // 2 MB (total ~456 MB)
  unsigned short* h2 = hhi;   // dead after xv gemm
  unsigned short* gb = hlo;   // dead after Qt gemm
  float* out = (float*)d_out;

  // weight converts
  cvt_kernel<<<dim3(256),  dim3(256), 0, stream>>>(qk_w, wqh, wql, 65536);
  cvt_kernel<<<dim3(1024), dim3(256), 0, stream>>>(v_w, wv, nullptr, 262144);
  cvt_kernel<<<dim3(256),  dim3(256), 0, stream>>>(t1_w, wt1h, wt1l, 65536);
  cvt_kernel<<<dim3(256),  dim3(256), 0, stream>>>(t2_w, wt2h, wt2l, 65536);
  cvt_kernel<<<dim3(1024), dim3(256), 0, stream>>>(m1_w, wm1, nullptr, 262144);
  cvt_kernel<<<dim3(1024), dim3(256), 0, stream>>>(m2_w, wm2, nullptr, 262144);
  // h = LN1(x) -> hi/lo
  ln_kernel<<<dim3(32768), dim3(256), 0, stream>>>(x, ln1_g, ln1_b, hhi, hlo);
  // Qt[b](256x4096) = qk_w @ h[b]^T   (split, hi/lo out)
  gemm16<4, 1><<<dim3(32, 2, 8), dim3(256), 0, stream>>>(
      wqh, wql, hhi, hlo, Qthi, Qtlo, nullptr, nullptr,
      1024, 1024, 1024, 4096, 0, 4194304, 1048576, 0, 1);
  // xv(32768x1024) = h @ v_w^T + v_b  (f16)
  gemm16<0, 0><<<dim3(8, 256, 1), dim3(256), 0, stream>>>(
      hhi, nullptr, wv, nullptr, xv, nullptr, v_b, nullptr,
      1024, 1024, 1024, 1024, 0, 0, 0, 0, 1);
  // energy partials: part[b*8+s](256x256) = Qt[b] @ Qt[b]^T over k-chunk s
  gemm16<5, 1><<<dim3(2, 2, 64), dim3(256), 0, stream>>>(
      Qthi, Qtlo, Qthi, Qtlo, part, nullptr, nullptr, nullptr,
      4096, 4096, 4096, 256, 1048576, 1048576, 65536, 0, 8);
  ereduce_kernel<<<dim3(2048), dim3(256), 0, stream>>>(part, Ehi, Elo);
  // G[b](1024x256) = gelu(t1_w @ en[b] + t1_b)  (en symmetric -> NT; split out)
  gemm16<6, 1><<<dim3(2, 8, 8), dim3(256), 0, stream>>>(
      wt1h, wt1l, Ehi, Elo, Ghi, Glo, t1_b, nullptr,
      256, 256, 256, 256, 0, 65536, 262144, 0, 1);
  // a2[b](1024x1024) = t2_w @ G[b]^T + t2_b  (f32 out)
  gemm16<7, 1><<<dim3(8, 8, 8), dim3(256), 0, stream>>>(
      wt2h, wt2l, Ghi, Glo, a2, nullptr, t2_b, nullptr,
      256, 256, 256, 1024, 0, 262144, 1048576, 0, 1);
  // attT[b] = softmax(a2[b], -1)^T  (f16)
  smax_t_kernel<<<dim3(128, 8), dim3(256), 0, stream>>>(a2, attT);
  // x1[b](4096x1024,f32) = xv[b] @ attT[b]^T + x[b]
  gemm16<2, 0><<<dim3(8, 32, 8), dim3(256), 0, stream>>>(
      xv, nullptr, attT, nullptr, x1, nullptr, nullptr, x,
      1024, 1024, 1024, 1024, 4194304, 1048576, 4194304, 4194304, 1);
  // h2 = LN2(x1) (f16 hi only)
  ln_kernel<<<dim3(32768), dim3(256), 0, stream>>>(x1, ln2_g, ln2_b, h2, nullptr);
  // g = gelu(h2 @ m1_w^T + m1_b)
  gemm16<1, 0><<<dim3(8, 256, 1), dim3(256), 0, stream>>>(
      h2, nullptr, wm1, nullptr, gb, nullptr, m1_b, nullptr,
      1024, 1024, 1024, 1024, 0, 0, 0, 0, 1);
  // out = x1 + g @ m2_w^T + m2_b (f32)
  gemm16<3, 0><<<dim3(8, 256, 1), dim3(256), 0, stream>>>(
      gb, nullptr, wm2, nullptr, out, nullptr, m2_b, x1,
      1024, 1024, 1024, 1024, 0, 0, 0, 0, 1);
}

// Round 5
// 732.304 us; speedup vs baseline: 1.4072x; 1.0017x over previous
//
#include <hip/hip_runtime.h>

// ---------------------------------------------------------------------------
// Enhanced_transformer  B=8, N=4096, P=1024, P4=256  (all fp32 in/out)
//
// Logit path (Qt, energy, G, a2): fp16-SPLIT MFMA (hi+lo, 3 MFMA/pair).
// Value path (xv, x1, m1, m2): plain f16 MFMA, 256^2 tile, 8 waves,
// double-buffered LDS with stage-at-top-of-step (drain covered by 64 MFMA).
// ---------------------------------------------------------------------------

typedef __attribute__((ext_vector_type(4))) float f32x4;
typedef __attribute__((ext_vector_type(8))) _Float16 h16x8;
typedef __attribute__((ext_vector_type(8))) unsigned short u16x8;
typedef __attribute__((ext_vector_type(4))) unsigned short u16x4;

__device__ __forceinline__ unsigned short f2h(float f) {
  _Float16 h = (_Float16)f;
  return __builtin_bit_cast(unsigned short, h);
}
// returns hi in bits[15:0], lo in bits[31:16]
__device__ __forceinline__ unsigned split16(float f) {
  _Float16 h = (_Float16)f;
  _Float16 l = (_Float16)(f - (float)h);
  return (unsigned)__builtin_bit_cast(unsigned short, h) |
         ((unsigned)__builtin_bit_cast(unsigned short, l) << 16);
}
__device__ __forceinline__ float gelu_f(float x) {
  return 0.5f * x * (1.0f + erff(x * 0.70710678118654752f));
}
__device__ __forceinline__ void gload16(const void* g, void* l) {
  __builtin_amdgcn_global_load_lds(
      (const __attribute__((address_space(1))) unsigned int*)g,
      (__attribute__((address_space(3))) unsigned int*)l, 16, 0, 0);
}

// ---------------- LayerNorm: row of 1024, out = f16 hi (+ optional lo) -----
__global__ __launch_bounds__(256)
void ln_kernel(const float* __restrict__ x, const float* __restrict__ g,
               const float* __restrict__ b, unsigned short* __restrict__ hi,
               unsigned short* __restrict__ lo) {
  __shared__ float red[16];
  const size_t base = (size_t)blockIdx.x * 1024;
  const int t = threadIdx.x;
  f32x4 v = *(const f32x4*)&x[base + t * 4];
  float s = v[0] + v[1] + v[2] + v[3];
  float q = v[0] * v[0] + v[1] * v[1] + v[2] * v[2] + v[3] * v[3];
#pragma unroll
  for (int o = 32; o > 0; o >>= 1) { s += __shfl_down(s, o); q += __shfl_down(q, o); }
  const int w = t >> 6;
  if ((t & 63) == 0) { red[w] = s; red[8 + w] = q; }
  __syncthreads();
  s = (red[0] + red[1]) + (red[2] + red[3]);
  q = (red[8] + red[9]) + (red[10] + red[11]);
  const float mu = s * (1.0f / 1024.0f);
  const float var = q * (1.0f / 1024.0f) - mu * mu;
  const float is = rsqrtf(var + 1e-5f);
  f32x4 gg = *(const f32x4*)&g[t * 4];
  f32x4 bb = *(const f32x4*)&b[t * 4];
  u16x4 oh, ol;
#pragma unroll
  for (int j = 0; j < 4; j++) {
    float y = (v[j] - mu) * is * gg[j] + bb[j];
    unsigned p = split16(y);
    oh[j] = (unsigned short)(p & 0xffffu);
    ol[j] = (unsigned short)(p >> 16);
  }
  *(u16x4*)&hi[base + t * 4] = oh;
  if (lo) *(u16x4*)&lo[base + t * 4] = ol;
}

// ---------------- fp32 -> f16 (hi + optional lo) ---------------------------
__global__ __launch_bounds__(256)
void cvt_kernel(const float* __restrict__ in, unsigned short* __restrict__ hi,
                unsigned short* __restrict__ lo, int n4) {
  int i = blockIdx.x * 256 + threadIdx.x;
  if (i < n4) {
    f32x4 v = *(const f32x4*)&in[(size_t)i * 4];
    u16x4 oh, ol;
#pragma unroll
    for (int j = 0; j < 4; j++) {
      unsigned p = split16(v[j]);
      oh[j] = (unsigned short)(p & 0xffffu);
      ol[j] = (unsigned short)(p >> 16);
    }
    *(u16x4*)&hi[(size_t)i * 4] = oh;
    if (lo) *(u16x4*)&lo[(size_t)i * 4] = ol;
  }
}

// ================= value-path GEMM: C = A(MxK) * B(NxK)^T ==================
// 256x256 tile, BK=64, 512 thr, 8 waves (2M x 4N), per-wave 128x64 out.
// Double-buffered LDS (128 KB); stage(next) issued before compute(cur);
// vmcnt(0)+barrier at step end (drain covered by 64 MFMA/wave).
// EPI: 0 f16 out +bias[col] | 1 f16 +bias +gelu | 2 f32 +res | 3 f32 +bias +res
template <int EPI>
__global__ __launch_bounds__(512)
void gemm_v(const unsigned short* __restrict__ Ain, const unsigned short* __restrict__ Bin,
            void* __restrict__ Cout, const float* __restrict__ bias,
            const float* __restrict__ resIn,
            int K, int lda, int ldb, int ldc,
            long long sA, long long sB, long long sC, long long sRes) {
  __shared__ short As[2][16384];   // 256 rows x 64 cols per buffer
  __shared__ short Bs[2][16384];
  const int z = blockIdx.z;
  const unsigned short* A = Ain + (size_t)z * sA;
  const unsigned short* B = Bin + (size_t)z * sB;
  int bx = blockIdx.x, by = blockIdx.y;
  {
    const int nwg = gridDim.x * gridDim.y;
    if ((nwg & 7) == 0 && nwg >= 16) {
      const int flat = bx + gridDim.x * by;
      const int chunk = nwg >> 3;
      const int nf = (flat & 7) * chunk + (flat >> 3);
      bx = nf % gridDim.x;
      by = nf / gridDim.x;
    }
  }
  const int mBase = by * 256, nBase = bx * 256;
  const int t = threadIdx.x, w = t >> 6, l = t & 63;
  const int r16 = l & 15, kq = l >> 4;
  const int wr = (w >> 2) * 128, wc = (w & 3) * 64;
  f32x4 acc[8][4] = {};

  auto stage = [&](int buf, int k0) {
#pragma unroll
    for (int i = 0; i < 4; ++i) {
      const int c = i * 512 + t;             // chunk id in 256x64 tile (8B f16 chunks)
      const int row = c >> 3, cc = c & 7;
      const int gc = cc ^ (row & 7);         // source-side swizzle
      const int cbase = i * 512 + w * 64;    // wave-uniform LDS base
      gload16(&A[(size_t)(mBase + row) * lda + k0 + gc * 8], &As[buf][cbase * 8]);
      gload16(&B[(size_t)(nBase + row) * ldb + k0 + gc * 8], &Bs[buf][cbase * 8]);
    }
  };

  const int nt = K >> 6;
  stage(0, 0);
  asm volatile("s_waitcnt vmcnt(0)" ::: "memory");
  __syncthreads();
  for (int ts = 0; ts < nt; ++ts) {
    const int cur = ts & 1;
    if (ts + 1 < nt) stage(cur ^ 1, (ts + 1) * 64);
#pragma unroll
    for (int kk = 0; kk < 2; ++kk) {
      h16x8 aF[8], bF[4];
#pragma unroll
      for (int ni = 0; ni < 4; ni++) {
        const int r = wc + ni * 16 + r16;
        bF[ni] = *(const h16x8*)&Bs[cur][r * 64 + (((kk * 4 + kq) ^ (r & 7))) * 8];
      }
#pragma unroll
      for (int mi = 0; mi < 8; mi++) {
        const int r = wr + mi * 16 + r16;
        aF[mi] = *(const h16x8*)&As[cur][r * 64 + (((kk * 4 + kq) ^ (r & 7))) * 8];
      }
#pragma unroll
      for (int mi = 0; mi < 8; mi++)
#pragma unroll
        for (int ni = 0; ni < 4; ni++)
          acc[mi][ni] = __builtin_amdgcn_mfma_f32_16x16x32_f16(aF[mi], bF[ni], acc[mi][ni], 0, 0, 0);
    }
    asm volatile("s_waitcnt vmcnt(0)" ::: "memory");
    __syncthreads();
  }

  unsigned short* C16 = (unsigned short*)Cout + (size_t)z * sC;
  float* C32 = (float*)Cout + (size_t)z * sC;
  const float* res = (EPI >= 2) ? (resIn + (size_t)z * sRes) : nullptr;
#pragma unroll
  for (int mi = 0; mi < 8; mi++) {
#pragma unroll
    for (int ni = 0; ni < 4; ni++) {
      const int cl = nBase + wc + ni * 16 + r16;
      const float bcol = (EPI != 2) ? bias[cl] : 0.0f;
#pragma unroll
      for (int r = 0; r < 4; r++) {
        const int rw = mBase + wr + mi * 16 + kq * 4 + r;  // C/D: row=(l>>4)*4+r, col=l&15
        float v = acc[mi][ni][r] + bcol;
        if (EPI == 1) v = gelu_f(v);
        if (EPI >= 2) v += res[(size_t)rw * ldc + cl];
        if (EPI <= 1) C16[(size_t)rw * ldc + cl] = f2h(v);
        else          C32[(size_t)rw * ldc + cl] = v;
      }
    }
  }
}

// ================= split-path GEMM: C = A(MxK) * B(NxK)^T ==================
// fp16-split hi/lo, 128x128 tile, BK=32, 4 waves (2x2), dbuf LDS (64 KB),
// stage(next) before compute(cur), drain at step end.
// EPI: 4 f16 hi/lo out | 5 f32 out | 6 f16 hi/lo +bias[row] +gelu | 7 f32 +bias[row]
template <int EPI>
__global__ __launch_bounds__(256)
void gemm_s(const unsigned short* __restrict__ Ahi, const unsigned short* __restrict__ Alo,
            const unsigned short* __restrict__ Bhi, const unsigned short* __restrict__ Blo,
            void* __restrict__ Cout, unsigned short* __restrict__ Cout2,
            const float* __restrict__ bias,
            int K, int lda, int ldb, int ldc,
            long long sA, long long sB, long long sC, int splitK) {
  __shared__ short As[2][8192];   // [buf][plane(hi 0 / lo 4096)][128x32]
  __shared__ short Bs[2][8192];
  const int z = blockIdx.z;
  const int bi = z / splitK, sp = z % splitK;
  const int kLen = K / splitK, kStart = sp * kLen;
  const unsigned short* AH = Ahi + (size_t)bi * sA;
  const unsigned short* BH = Bhi + (size_t)bi * sB;
  const unsigned short* AL = Alo + (size_t)bi * sA;
  const unsigned short* BL = Blo + (size_t)bi * sB;
  int bx = blockIdx.x, by = blockIdx.y;
  {
    const int nwg = gridDim.x * gridDim.y;
    if ((nwg & 7) == 0 && nwg >= 16) {
      const int flat = bx + gridDim.x * by;
      const int chunk = nwg >> 3;
      const int nf = (flat & 7) * chunk + (flat >> 3);
      bx = nf % gridDim.x;
      by = nf / gridDim.x;
    }
  }
  const int mBase = by * 128, nBase = bx * 128;
  const int t = threadIdx.x, w = t >> 6, l = t & 63;
  const int r16 = l & 15, kq = l >> 4;
  const int wr = (w >> 1) * 64, wc = (w & 1) * 64;
  f32x4 acc[4][4] = {};

  auto stage = [&](int buf, int k0) {
#pragma unroll
    for (int i = 0; i < 2; ++i) {
      const int c = i * 256 + t;             // chunk in 128x32 plane (512 chunks)
      const int row = c >> 2, cc = c & 3;
      const int gc = cc ^ ((row >> 1) & 3);  // source-side swizzle
      const int cbase = i * 256 + w * 64;    // wave-uniform
      const size_t ga = (size_t)(mBase + row) * lda + k0 + gc * 8;
      const size_t gb = (size_t)(nBase + row) * ldb + k0 + gc * 8;
      gload16(&AH[ga], &As[buf][cbase * 8]);
      gload16(&AL[ga], &As[buf][4096 + cbase * 8]);
      gload16(&BH[gb], &Bs[buf][cbase * 8]);
      gload16(&BL[gb], &Bs[buf][4096 + cbase * 8]);
    }
  };

  const int nsteps = kLen >> 5;
  stage(0, kStart);
  asm volatile("s_waitcnt vmcnt(0)" ::: "memory");
  __syncthreads();
  for (int ts = 0; ts < nsteps; ++ts) {
    const int cur = ts & 1;
    if (ts + 1 < nsteps) stage(cur ^ 1, kStart + (ts + 1) * 32);
    h16x8 aH[4], bH[4], aL[4], bL[4];
#pragma unroll
    for (int mi = 0; mi < 4; mi++) {
      const int r = wr + mi * 16 + r16;
      const int off = r * 32 + (kq ^ ((r >> 1) & 3)) * 8;
      aH[mi] = *(const h16x8*)&As[cur][off];
      aL[mi] = *(const h16x8*)&As[cur][4096 + off];
    }
#pragma unroll
    for (int ni = 0; ni < 4; ni++) {
      const int r = wc + ni * 16 + r16;
      const int off = r * 32 + (kq ^ ((r >> 1) & 3)) * 8;
      bH[ni] = *(const h16x8*)&Bs[cur][off];
      bL[ni] = *(const h16x8*)&Bs[cur][4096 + off];
    }
#pragma unroll
    for (int mi = 0; mi < 4; mi++)
#pragma unroll
      for (int ni = 0; ni < 4; ni++) {
        acc[mi][ni] = __builtin_amdgcn_mfma_f32_16x16x32_f16(aH[mi], bH[ni], acc[mi][ni], 0, 0, 0);
        acc[mi][ni] = __builtin_amdgcn_mfma_f32_16x16x32_f16(aH[mi], bL[ni], acc[mi][ni], 0, 0, 0);
        acc[mi][ni] = __builtin_amdgcn_mfma_f32_16x16x32_f16(aL[mi], bH[ni], acc[mi][ni], 0, 0, 0);
      }
    asm volatile("s_waitcnt vmcnt(0)" ::: "memory");
    __syncthreads();
  }

  unsigned short* C16 = (unsigned short*)Cout + (size_t)z * sC;
  unsigned short* C16b = Cout2 ? Cout2 + (size_t)z * sC : nullptr;
  float* C32 = (float*)Cout + (size_t)z * sC;
#pragma unroll
  for (int mi = 0; mi < 4; mi++) {
#pragma unroll
    for (int ni = 0; ni < 4; ni++) {
      const int cl = nBase + wc + ni * 16 + r16;
#pragma unroll
      for (int r = 0; r < 4; r++) {
        const int rw = mBase + wr + mi * 16 + kq * 4 + r;
        float v = acc[mi][ni][r];
        if (EPI == 6 || EPI == 7) v += bias[rw];
        if (EPI == 6) v = gelu_f(v);
        const size_t idx = (size_t)rw * ldc + cl;
        if (EPI == 4 || EPI == 6) {
          unsigned p = split16(v);
          C16[idx] = (unsigned short)(p & 0xffffu);
          C16b[idx] = (unsigned short)(p >> 16);
        } else {
          C32[idx] = v;
        }
      }
    }
  }
}

// ---------------- energy split-K reduce -> f16 hi/lo -----------------------
__global__ __launch_bounds__(256)
void ereduce_kernel(const float* __restrict__ part, unsigned short* __restrict__ ehi,
                    unsigned short* __restrict__ elo) {
  const size_t idx = (size_t)blockIdx.x * 256 + threadIdx.x;  // 8*65536 total
  const size_t b = idx >> 16, i = idx & 65535;
  const float* p = part + b * (8ull * 65536) + i;
  float s0 = (p[0] + p[65536]) + (p[2 * 65536] + p[3 * 65536]);
  float s1 = (p[4 * 65536] + p[5 * 65536]) + (p[6 * 65536] + p[7 * 65536]);
  unsigned pk = split16(s0 + s1);
  ehi[idx] = (unsigned short)(pk & 0xffffu);
  elo[idx] = (unsigned short)(pk >> 16);
}

// ---------------- softmax over rows + transpose -> f16 ---------------------
__global__ __launch_bounds__(256)
void smax_t_kernel(const float* __restrict__ a2, unsigned short* __restrict__ attT) {
  __shared__ float S[8][1028];
  __shared__ float inv[8];
  const int t = threadIdx.x;
  const int b = blockIdx.y;
  const int o0 = blockIdx.x * 8;
  const float* src = a2 + ((size_t)b * 1024 + o0) * 1024;
#pragma unroll
  for (int i = 0; i < 8; i++)
    *(f32x4*)&S[i][t * 4] = *(const f32x4*)&src[(size_t)i * 1024 + t * 4];
  __syncthreads();
  const int w = t >> 6, l = t & 63;
  for (int rr = 0; rr < 2; rr++) {
    const int r = w * 2 + rr;
    float m = -1e30f;
#pragma unroll
    for (int i = 0; i < 16; i++) m = fmaxf(m, S[r][l + i * 64]);
#pragma unroll
    for (int o = 32; o > 0; o >>= 1) m = fmaxf(m, __shfl_xor(m, o));
    float ssum = 0.0f;
#pragma unroll
    for (int i = 0; i < 16; i++) {
      float e = expf(S[r][l + i * 64] - m);
      S[r][l + i * 64] = e;
      ssum += e;
    }
#pragma unroll
    for (int o = 32; o > 0; o >>= 1) ssum += __shfl_xor(ssum, o);
    if (l == 0) inv[r] = 1.0f / ssum;
  }
  __syncthreads();
  float iv[8];
#pragma unroll
  for (int r = 0; r < 8; r++) iv[r] = inv[r];
#pragma unroll
  for (int i = 0; i < 4; i++) {
    const int k = i * 256 + t;
    u16x8 ov;
#pragma unroll
    for (int r = 0; r < 8; r++) ov[r] = f2h(S[r][k] * iv[r]);
    *(u16x8*)&attT[((size_t)b * 1024 + k) * 1024 + o0] = ov;
  }
}

// ---------------------------------------------------------------------------
extern "C" void kernel_launch(void* const* d_in, const int* in_sizes, int n_in,
                              void* d_out, int out_size, void* d_ws, size_t ws_size,
                              hipStream_t stream) {
  (void)in_sizes; (void)n_in; (void)out_size; (void)ws_size;
  const float* x     = (const float*)d_in[1];
  const float* ln1_g = (const float*)d_in[2];
  const float* ln1_b = (const float*)d_in[3];
  const float* ln2_g = (const float*)d_in[4];
  const float* ln2_b = (const float*)d_in[5];
  const float* qk_w  = (const float*)d_in[6];
  const float* v_w   = (const float*)d_in[7];
  const float* v_b   = (const float*)d_in[8];
  const float* t1_w  = (const float*)d_in[9];
  const float* t1_b  = (const float*)d_in[10];
  const float* t2_w  = (const float*)d_in[11];
  const float* t2_b  = (const float*)d_in[12];
  const float* m1_w  = (const float*)d_in[13];
  const float* m1_b  = (const float*)d_in[14];
  const float* m2_w  = (const float*)d_in[15];
  const float* m2_b  = (const float*)d_in[16];

  char* ws = (char*)d_ws;
  unsigned short* hhi  = (unsigned short*)(ws + 0);            // 67 MB (-> h2)
  unsigned short* hlo  = (unsigned short*)(ws + 67108864);     // 67 MB (-> g)
  unsigned short* Qthi = (unsigned short*)(ws + 134217728);    // 16.8 MB
  unsigned short* Qtlo = (unsigned short*)(ws + 150994944);    // 16.8 MB
  float*          part = (float*)(ws + 167772160);             // 16.8 MB
  unsigned short* Ehi  = (unsigned short*)(ws + 184549376);    // 1 MB
  unsigned short* Elo  = (unsigned short*)(ws + 185597952);    // 1 MB
  unsigned short* Ghi  = (unsigned short*)(ws + 186646528);    // 4.2 MB
  unsigned short* Glo  = (unsigned short*)(ws + 190840832);    // 4.2 MB
  float*          a2   = (float*)(ws + 195035136);             // 33.5 MB
  unsigned short* attT = (unsigned short*)(ws + 228589568);    // 16.8 MB
  unsigned short* xv   = (unsigned short*)(ws + 245366784);    // 67 MB
  float*          x1   = (float*)(ws + 312475648);             // 134 MB
  unsigned short* wqh  = (unsigned short*)(ws + 446693376);    // 0.5 MB
  unsigned short* wql  = (unsigned short*)(ws + 447217664);
  unsigned short* wv   = (unsigned short*)(ws + 447741952);    // 2 MB
  unsigned short* wt1h = (unsigned short*)(ws + 449839104);
  unsigned short* wt1l = (unsigned short*)(ws + 450363392);
  unsigned short* wt2h = (unsigned short*)(ws + 450887680);
  unsigned short* wt2l = (unsigned short*)(ws + 451411968);
  unsigned short* wm1  = (unsigned short*)(ws + 451936256);    // 2 MB
  unsigned short* wm2  = (unsigned short*)(ws + 454033408);    // 2 MB (total ~456 MB)
  unsigned short* h2 = hhi;   // dead after xv gemm
  unsigned short* gb = hlo;   // dead after Qt gemm
  float* out = (float*)d_out;

  // weight converts
  cvt_kernel<<<dim3(256),  dim3(256), 0, stream>>>(qk_w, wqh, wql, 65536);
  cvt_kernel<<<dim3(1024), dim3(256), 0, stream>>>(v_w, wv, nullptr, 262144);
  cvt_kernel<<<dim3(256),  dim3(256), 0, stream>>>(t1_w, wt1h, wt1l, 65536);
  cvt_kernel<<<dim3(256),  dim3(256), 0, stream>>>(t2_w, wt2h, wt2l, 65536);
  cvt_kernel<<<dim3(1024), dim3(256), 0, stream>>>(m1_w, wm1, nullptr, 262144);
  cvt_kernel<<<dim3(1024), dim3(256), 0, stream>>>(m2_w, wm2, nullptr, 262144);
  // h = LN1(x) -> hi/lo
  ln_kernel<<<dim3(32768), dim3(256), 0, stream>>>(x, ln1_g, ln1_b, hhi, hlo);
  // Qt[b](256x4096) = qk_w @ h[b]^T   (split, hi/lo out)
  gemm_s<4><<<dim3(32, 2, 8), dim3(256), 0, stream>>>(
      wqh, wql, hhi, hlo, Qthi, Qtlo, nullptr,
      1024, 1024, 1024, 4096, 0, 4194304, 1048576, 1);
  // xv(32768x1024) = h @ v_w^T + v_b  (f16)
  gemm_v<0><<<dim3(4, 128, 1), dim3(512), 0, stream>>>(
      hhi, wv, xv, v_b, nullptr, 1024, 1024, 1024, 1024, 0, 0, 0, 0);
  // energy partials: part[b*8+s](256x256) = Qt[b] @ Qt[b]^T over k-chunk s
  gemm_s<5><<<dim3(2, 2, 64), dim3(256), 0, stream>>>(
      Qthi, Qtlo, Qthi, Qtlo, part, nullptr, nullptr,
      4096, 4096, 4096, 256, 1048576, 1048576, 65536, 8);
  ereduce_kernel<<<dim3(2048), dim3(256), 0, stream>>>(part, Ehi, Elo);
  // G[b](1024x256) = gelu(t1_w @ en[b] + t1_b)  (en symmetric -> NT; split out)
  gemm_s<6><<<dim3(2, 8, 8), dim3(256), 0, stream>>>(
      wt1h, wt1l, Ehi, Elo, Ghi, Glo, t1_b,
      256, 256, 256, 256, 0, 65536, 262144, 1);
  // a2[b](1024x1024) = t2_w @ G[b]^T + t2_b  (f32 out)
  gemm_s<7><<<dim3(8, 8, 8), dim3(256), 0, stream>>>(
      wt2h, wt2l, Ghi, Glo, a2, nullptr, t2_b,
      256, 256, 256, 1024, 0, 262144, 1048576, 1);
  // attT[b] = softmax(a2[b], -1)^T  (f16)
  smax_t_kernel<<<dim3(128, 8), dim3(256), 0, stream>>>(a2, attT);
  // x1[b](4096x1024,f32) = xv[b] @ attT[b]^T + x[b]
  gemm_v<2><<<dim3(4, 16, 8), dim3(512), 0, stream>>>(
      xv, attT, x1, nullptr, x, 1024, 1024, 1024, 1024, 4194304, 1048576, 4194304, 4194304);
  // h2 = LN2(x1) (f16 hi only)
  ln_kernel<<<dim3(32768), dim3(256), 0, stream>>>(x1, ln2_g, ln2_b, h2, nullptr);
  // g = gelu(h2 @ m1_w^T + m1_b)
  gemm_v<1><<<dim3(4, 128, 1), dim3(512), 0, stream>>>(
      h2, wm1, gb, m1_b, nullptr, 1024, 1024, 1024, 1024, 0, 0, 0, 0);
  // out = x1 + g @ m2_w^T + m2_b (f32)
  gemm_v<3><<<dim3(4, 128, 1), dim3(512), 0, stream>>>(
      gb, wm2, out, m2_b, x1, 1024, 1024, 1024, 1024, 0, 0, 0, 0);
}

// Round 6
// 720.667 us; speedup vs baseline: 1.4299x; 1.0161x over previous
//
#include <hip/hip_runtime.h>

// ---------------------------------------------------------------------------
// Enhanced_transformer  B=8, N=4096, P=1024, P4=256  (all fp32 in/out)
//
// Logit path (Qt, energy, G, a2): fp16-SPLIT MFMA (hi+lo, 3 MFMA/pair).
// Value path (xv, x1, m1, m2): plain f16 MFMA, 256^2 tile, 8 waves.
// R6: counted-vmcnt pipeline (T4): vmcnt(8) + raw s_barrier per step, loads
// for step t+2 stay in flight across two compute phases. No drain-to-0 in
// the main loop (m218: counted-vs-drain0 = +38..73%).
// ---------------------------------------------------------------------------

typedef __attribute__((ext_vector_type(4))) float f32x4;
typedef __attribute__((ext_vector_type(8))) _Float16 h16x8;
typedef __attribute__((ext_vector_type(8))) unsigned short u16x8;
typedef __attribute__((ext_vector_type(4))) unsigned short u16x4;

__device__ __forceinline__ unsigned short f2h(float f) {
  _Float16 h = (_Float16)f;
  return __builtin_bit_cast(unsigned short, h);
}
// returns hi in bits[15:0], lo in bits[31:16]
__device__ __forceinline__ unsigned split16(float f) {
  _Float16 h = (_Float16)f;
  _Float16 l = (_Float16)(f - (float)h);
  return (unsigned)__builtin_bit_cast(unsigned short, h) |
         ((unsigned)__builtin_bit_cast(unsigned short, l) << 16);
}
__device__ __forceinline__ float gelu_f(float x) {
  return 0.5f * x * (1.0f + erff(x * 0.70710678118654752f));
}
__device__ __forceinline__ void gload16(const void* g, void* l) {
  __builtin_amdgcn_global_load_lds(
      (const __attribute__((address_space(1))) unsigned int*)g,
      (__attribute__((address_space(3))) unsigned int*)l, 16, 0, 0);
}
#define FENCE() asm volatile("" ::: "memory")

// ---------------- LayerNorm: row of 1024, out = f16 hi (+ optional lo) -----
__global__ __launch_bounds__(256)
void ln_kernel(const float* __restrict__ x, const float* __restrict__ g,
               const float* __restrict__ b, unsigned short* __restrict__ hi,
               unsigned short* __restrict__ lo) {
  __shared__ float red[16];
  const size_t base = (size_t)blockIdx.x * 1024;
  const int t = threadIdx.x;
  f32x4 v = *(const f32x4*)&x[base + t * 4];
  float s = v[0] + v[1] + v[2] + v[3];
  float q = v[0] * v[0] + v[1] * v[1] + v[2] * v[2] + v[3] * v[3];
#pragma unroll
  for (int o = 32; o > 0; o >>= 1) { s += __shfl_down(s, o); q += __shfl_down(q, o); }
  const int w = t >> 6;
  if ((t & 63) == 0) { red[w] = s; red[8 + w] = q; }
  __syncthreads();
  s = (red[0] + red[1]) + (red[2] + red[3]);
  q = (red[8] + red[9]) + (red[10] + red[11]);
  const float mu = s * (1.0f / 1024.0f);
  const float var = q * (1.0f / 1024.0f) - mu * mu;
  const float is = rsqrtf(var + 1e-5f);
  f32x4 gg = *(const f32x4*)&g[t * 4];
  f32x4 bb = *(const f32x4*)&b[t * 4];
  u16x4 oh, ol;
#pragma unroll
  for (int j = 0; j < 4; j++) {
    float y = (v[j] - mu) * is * gg[j] + bb[j];
    unsigned p = split16(y);
    oh[j] = (unsigned short)(p & 0xffffu);
    ol[j] = (unsigned short)(p >> 16);
  }
  *(u16x4*)&hi[base + t * 4] = oh;
  if (lo) *(u16x4*)&lo[base + t * 4] = ol;
}

// ---------------- fp32 -> f16 (hi + optional lo) ---------------------------
__global__ __launch_bounds__(256)
void cvt_kernel(const float* __restrict__ in, unsigned short* __restrict__ hi,
                unsigned short* __restrict__ lo, int n4) {
  int i = blockIdx.x * 256 + threadIdx.x;
  if (i < n4) {
    f32x4 v = *(const f32x4*)&in[(size_t)i * 4];
    u16x4 oh, ol;
#pragma unroll
    for (int j = 0; j < 4; j++) {
      unsigned p = split16(v[j]);
      oh[j] = (unsigned short)(p & 0xffffu);
      ol[j] = (unsigned short)(p >> 16);
    }
    *(u16x4*)&hi[(size_t)i * 4] = oh;
    if (lo) *(u16x4*)&lo[(size_t)i * 4] = ol;
  }
}

// ================= value-path GEMM: C = A(MxK) * B(NxK)^T ==================
// 256x256 tile, BK=64, 512 thr, 8 waves (2M x 4N), per-wave 128x64 out.
// Double-buffered LDS; counted vmcnt(8) pipeline, stage(t+2) after barrier2.
// EPI: 0 f16 out +bias[col] | 1 f16 +bias +gelu | 2 f32 +res | 3 f32 +bias +res
template <int EPI>
__global__ __launch_bounds__(512)
void gemm_v(const unsigned short* __restrict__ Ain, const unsigned short* __restrict__ Bin,
            void* __restrict__ Cout, const float* __restrict__ bias,
            const float* __restrict__ resIn,
            int K, int lda, int ldb, int ldc,
            long long sA, long long sB, long long sC, long long sRes) {
  __shared__ short As[2][16384];   // 256 rows x 64 cols per buffer
  __shared__ short Bs[2][16384];
  const int z = blockIdx.z;
  const unsigned short* A = Ain + (size_t)z * sA;
  const unsigned short* B = Bin + (size_t)z * sB;
  int bx = blockIdx.x, by = blockIdx.y;
  {
    const int nwg = gridDim.x * gridDim.y;
    if ((nwg & 7) == 0 && nwg >= 16) {
      const int flat = bx + gridDim.x * by;
      const int chunk = nwg >> 3;
      const int nf = (flat & 7) * chunk + (flat >> 3);
      bx = nf % gridDim.x;
      by = nf / gridDim.x;
    }
  }
  const int mBase = by * 256, nBase = bx * 256;
  const int t = threadIdx.x, w = t >> 6, l = t & 63;
  const int r16 = l & 15, kq = l >> 4;
  const int wr = (w >> 2) * 128, wc = (w & 3) * 64;
  f32x4 acc[8][4] = {};

  auto stage = [&](int buf, int k0) {   // 8 vector-mem instrs per wave
#pragma unroll
    for (int i = 0; i < 4; ++i) {
      const int c = i * 512 + t;             // chunk id in 256x64 tile (8B f16 chunks)
      const int row = c >> 3, cc = c & 7;
      const int gc = cc ^ (row & 7);         // source-side swizzle
      const int cbase = i * 512 + w * 64;    // wave-uniform LDS base
      gload16(&A[(size_t)(mBase + row) * lda + k0 + gc * 8], &As[buf][cbase * 8]);
      gload16(&B[(size_t)(nBase + row) * ldb + k0 + gc * 8], &Bs[buf][cbase * 8]);
    }
  };

  const int nt = K >> 6;
  stage(0, 0);
  if (nt > 1) stage(1, 64);
  for (int ts = 0; ts < nt; ++ts) {
    const int cur = ts & 1;
    if (ts + 1 < nt) { asm volatile("s_waitcnt vmcnt(8)" ::: "memory"); }
    else             { asm volatile("s_waitcnt vmcnt(0)" ::: "memory"); }
    __builtin_amdgcn_s_barrier();
    FENCE();
#pragma unroll
    for (int kk = 0; kk < 2; ++kk) {
      h16x8 aF[8], bF[4];
#pragma unroll
      for (int ni = 0; ni < 4; ni++) {
        const int r = wc + ni * 16 + r16;
        bF[ni] = *(const h16x8*)&Bs[cur][r * 64 + (((kk * 4 + kq) ^ (r & 7))) * 8];
      }
#pragma unroll
      for (int mi = 0; mi < 8; mi++) {
        const int r = wr + mi * 16 + r16;
        aF[mi] = *(const h16x8*)&As[cur][r * 64 + (((kk * 4 + kq) ^ (r & 7))) * 8];
      }
#pragma unroll
      for (int mi = 0; mi < 8; mi++)
#pragma unroll
        for (int ni = 0; ni < 4; ni++)
          acc[mi][ni] = __builtin_amdgcn_mfma_f32_16x16x32_f16(aF[mi], bF[ni], acc[mi][ni], 0, 0, 0);
    }
    FENCE();
    __builtin_amdgcn_s_barrier();
    FENCE();
    if (ts + 2 < nt) stage(cur, (ts + 2) * 64);
  }

  unsigned short* C16 = (unsigned short*)Cout + (size_t)z * sC;
  float* C32 = (float*)Cout + (size_t)z * sC;
  const float* res = (EPI >= 2) ? (resIn + (size_t)z * sRes) : nullptr;
#pragma unroll
  for (int mi = 0; mi < 8; mi++) {
#pragma unroll
    for (int ni = 0; ni < 4; ni++) {
      const int cl = nBase + wc + ni * 16 + r16;
      const float bcol = (EPI != 2) ? bias[cl] : 0.0f;
#pragma unroll
      for (int r = 0; r < 4; r++) {
        const int rw = mBase + wr + mi * 16 + kq * 4 + r;  // C/D: row=(l>>4)*4+r, col=l&15
        float v = acc[mi][ni][r] + bcol;
        if (EPI == 1) v = gelu_f(v);
        if (EPI >= 2) v += res[(size_t)rw * ldc + cl];
        if (EPI <= 1) C16[(size_t)rw * ldc + cl] = f2h(v);
        else          C32[(size_t)rw * ldc + cl] = v;
      }
    }
  }
}

// ================= split-path GEMM: C = A(MxK) * B(NxK)^T ==================
// fp16-split hi/lo, 128x128 tile, BK=32, 4 waves (2x2), dbuf LDS (64 KB),
// counted vmcnt(8) pipeline.
// EPI: 4 f16 hi/lo out | 5 f32 out | 6 f16 hi/lo +bias[row] +gelu | 7 f32 +bias[row]
template <int EPI>
__global__ __launch_bounds__(256)
void gemm_s(const unsigned short* __restrict__ Ahi, const unsigned short* __restrict__ Alo,
            const unsigned short* __restrict__ Bhi, const unsigned short* __restrict__ Blo,
            void* __restrict__ Cout, unsigned short* __restrict__ Cout2,
            const float* __restrict__ bias,
            int K, int lda, int ldb, int ldc,
            long long sA, long long sB, long long sC, int splitK) {
  __shared__ short As[2][8192];   // [buf][plane(hi 0 / lo 4096)][128x32]
  __shared__ short Bs[2][8192];
  const int z = blockIdx.z;
  const int bi = z / splitK, sp = z % splitK;
  const int kLen = K / splitK, kStart = sp * kLen;
  const unsigned short* AH = Ahi + (size_t)bi * sA;
  const unsigned short* BH = Bhi + (size_t)bi * sB;
  const unsigned short* AL = Alo + (size_t)bi * sA;
  const unsigned short* BL = Blo + (size_t)bi * sB;
  int bx = blockIdx.x, by = blockIdx.y;
  {
    const int nwg = gridDim.x * gridDim.y;
    if ((nwg & 7) == 0 && nwg >= 16) {
      const int flat = bx + gridDim.x * by;
      const int chunk = nwg >> 3;
      const int nf = (flat & 7) * chunk + (flat >> 3);
      bx = nf % gridDim.x;
      by = nf / gridDim.x;
    }
  }
  const int mBase = by * 128, nBase = bx * 128;
  const int t = threadIdx.x, w = t >> 6, l = t & 63;
  const int r16 = l & 15, kq = l >> 4;
  const int wr = (w >> 1) * 64, wc = (w & 1) * 64;
  f32x4 acc[4][4] = {};

  auto stage = [&](int buf, int k0) {   // 8 vector-mem instrs per wave
#pragma unroll
    for (int i = 0; i < 2; ++i) {
      const int c = i * 256 + t;             // chunk in 128x32 plane (512 chunks)
      const int row = c >> 2, cc = c & 3;
      const int gc = cc ^ ((row >> 1) & 3);  // source-side swizzle
      const int cbase = i * 256 + w * 64;    // wave-uniform
      const size_t ga = (size_t)(mBase + row) * lda + k0 + gc * 8;
      const size_t gb = (size_t)(nBase + row) * ldb + k0 + gc * 8;
      gload16(&AH[ga], &As[buf][cbase * 8]);
      gload16(&AL[ga], &As[buf][4096 + cbase * 8]);
      gload16(&BH[gb], &Bs[buf][cbase * 8]);
      gload16(&BL[gb], &Bs[buf][4096 + cbase * 8]);
    }
  };

  const int nsteps = kLen >> 5;
  stage(0, kStart);
  if (nsteps > 1) stage(1, kStart + 32);
  for (int ts = 0; ts < nsteps; ++ts) {
    const int cur = ts & 1;
    if (ts + 1 < nsteps) { asm volatile("s_waitcnt vmcnt(8)" ::: "memory"); }
    else                 { asm volatile("s_waitcnt vmcnt(0)" ::: "memory"); }
    __builtin_amdgcn_s_barrier();
    FENCE();
    h16x8 aH[4], bH[4], aL[4], bL[4];
#pragma unroll
    for (int mi = 0; mi < 4; mi++) {
      const int r = wr + mi * 16 + r16;
      const int off = r * 32 + (kq ^ ((r >> 1) & 3)) * 8;
      aH[mi] = *(const h16x8*)&As[cur][off];
      aL[mi] = *(const h16x8*)&As[cur][4096 + off];
    }
#pragma unroll
    for (int ni = 0; ni < 4; ni++) {
      const int r = wc + ni * 16 + r16;
      const int off = r * 32 + (kq ^ ((r >> 1) & 3)) * 8;
      bH[ni] = *(const h16x8*)&Bs[cur][off];
      bL[ni] = *(const h16x8*)&Bs[cur][4096 + off];
    }
#pragma unroll
    for (int mi = 0; mi < 4; mi++)
#pragma unroll
      for (int ni = 0; ni < 4; ni++) {
        acc[mi][ni] = __builtin_amdgcn_mfma_f32_16x16x32_f16(aH[mi], bH[ni], acc[mi][ni], 0, 0, 0);
        acc[mi][ni] = __builtin_amdgcn_mfma_f32_16x16x32_f16(aH[mi], bL[ni], acc[mi][ni], 0, 0, 0);
        acc[mi][ni] = __builtin_amdgcn_mfma_f32_16x16x32_f16(aL[mi], bH[ni], acc[mi][ni], 0, 0, 0);
      }
    FENCE();
    __builtin_amdgcn_s_barrier();
    FENCE();
    if (ts + 2 < nsteps) stage(cur, kStart + (ts + 2) * 32);
  }

  unsigned short* C16 = (unsigned short*)Cout + (size_t)z * sC;
  unsigned short* C16b = Cout2 ? Cout2 + (size_t)z * sC : nullptr;
  float* C32 = (float*)Cout + (size_t)z * sC;
#pragma unroll
  for (int mi = 0; mi < 4; mi++) {
#pragma unroll
    for (int ni = 0; ni < 4; ni++) {
      const int cl = nBase + wc + ni * 16 + r16;
#pragma unroll
      for (int r = 0; r < 4; r++) {
        const int rw = mBase + wr + mi * 16 + kq * 4 + r;
        float v = acc[mi][ni][r];
        if (EPI == 6 || EPI == 7) v += bias[rw];
        if (EPI == 6) v = gelu_f(v);
        const size_t idx = (size_t)rw * ldc + cl;
        if (EPI == 4 || EPI == 6) {
          unsigned p = split16(v);
          C16[idx] = (unsigned short)(p & 0xffffu);
          C16b[idx] = (unsigned short)(p >> 16);
        } else {
          C32[idx] = v;
        }
      }
    }
  }
}

// ---------------- energy split-K reduce -> f16 hi/lo -----------------------
__global__ __launch_bounds__(256)
void ereduce_kernel(const float* __restrict__ part, unsigned short* __restrict__ ehi,
                    unsigned short* __restrict__ elo) {
  const size_t idx = (size_t)blockIdx.x * 256 + threadIdx.x;  // 8*65536 total
  const size_t b = idx >> 16, i = idx & 65535;
  const float* p = part + b * (8ull * 65536) + i;
  float s0 = (p[0] + p[65536]) + (p[2 * 65536] + p[3 * 65536]);
  float s1 = (p[4 * 65536] + p[5 * 65536]) + (p[6 * 65536] + p[7 * 65536]);
  unsigned pk = split16(s0 + s1);
  ehi[idx] = (unsigned short)(pk & 0xffffu);
  elo[idx] = (unsigned short)(pk >> 16);
}

// ---------------- softmax over rows + transpose -> f16 ---------------------
__global__ __launch_bounds__(256)
void smax_t_kernel(const float* __restrict__ a2, unsigned short* __restrict__ attT) {
  __shared__ float S[8][1028];
  __shared__ float inv[8];
  const int t = threadIdx.x;
  const int b = blockIdx.y;
  const int o0 = blockIdx.x * 8;
  const float* src = a2 + ((size_t)b * 1024 + o0) * 1024;
#pragma unroll
  for (int i = 0; i < 8; i++)
    *(f32x4*)&S[i][t * 4] = *(const f32x4*)&src[(size_t)i * 1024 + t * 4];
  __syncthreads();
  const int w = t >> 6, l = t & 63;
  for (int rr = 0; rr < 2; rr++) {
    const int r = w * 2 + rr;
    float m = -1e30f;
#pragma unroll
    for (int i = 0; i < 16; i++) m = fmaxf(m, S[r][l + i * 64]);
#pragma unroll
    for (int o = 32; o > 0; o >>= 1) m = fmaxf(m, __shfl_xor(m, o));
    float ssum = 0.0f;
#pragma unroll
    for (int i = 0; i < 16; i++) {
      float e = expf(S[r][l + i * 64] - m);
      S[r][l + i * 64] = e;
      ssum += e;
    }
#pragma unroll
    for (int o = 32; o > 0; o >>= 1) ssum += __shfl_xor(ssum, o);
    if (l == 0) inv[r] = 1.0f / ssum;
  }
  __syncthreads();
  float iv[8];
#pragma unroll
  for (int r = 0; r < 8; r++) iv[r] = inv[r];
#pragma unroll
  for (int i = 0; i < 4; i++) {
    const int k = i * 256 + t;
    u16x8 ov;
#pragma unroll
    for (int r = 0; r < 8; r++) ov[r] = f2h(S[r][k] * iv[r]);
    *(u16x8*)&attT[((size_t)b * 1024 + k) * 1024 + o0] = ov;
  }
}

// ---------------------------------------------------------------------------
extern "C" void kernel_launch(void* const* d_in, const int* in_sizes, int n_in,
                              void* d_out, int out_size, void* d_ws, size_t ws_size,
                              hipStream_t stream) {
  (void)in_sizes; (void)n_in; (void)out_size; (void)ws_size;
  const float* x     = (const float*)d_in[1];
  const float* ln1_g = (const float*)d_in[2];
  const float* ln1_b = (const float*)d_in[3];
  const float* ln2_g = (const float*)d_in[4];
  const float* ln2_b = (const float*)d_in[5];
  const float* qk_w  = (const float*)d_in[6];
  const float* v_w   = (const float*)d_in[7];
  const float* v_b   = (const float*)d_in[8];
  const float* t1_w  = (const float*)d_in[9];
  const float* t1_b  = (const float*)d_in[10];
  const float* t2_w  = (const float*)d_in[11];
  const float* t2_b  = (const float*)d_in[12];
  const float* m1_w  = (const float*)d_in[13];
  const float* m1_b  = (const float*)d_in[14];
  const float* m2_w  = (const float*)d_in[15];
  const float* m2_b  = (const float*)d_in[16];

  char* ws = (char*)d_ws;
  unsigned short* hhi  = (unsigned short*)(ws + 0);            // 67 MB (-> h2)
  unsigned short* hlo  = (unsigned short*)(ws + 67108864);     // 67 MB (-> g)
  unsigned short* Qthi = (unsigned short*)(ws + 134217728);    // 16.8 MB
  unsigned short* Qtlo = (unsigned short*)(ws + 150994944);    // 16.8 MB
  float*          part = (float*)(ws + 167772160);             // 16.8 MB
  unsigned short* Ehi  = (unsigned short*)(ws + 184549376);    // 1 MB
  unsigned short* Elo  = (unsigned short*)(ws + 185597952);    // 1 MB
  unsigned short* Ghi  = (unsigned short*)(ws + 186646528);    // 4.2 MB
  unsigned short* Glo  = (unsigned short*)(ws + 190840832);    // 4.2 MB
  float*          a2   = (float*)(ws + 195035136);             // 33.5 MB
  unsigned short* attT = (unsigned short*)(ws + 228589568);    // 16.8 MB
  unsigned short* xv   = (unsigned short*)(ws + 245366784);    // 67 MB
  float*          x1   = (float*)(ws + 312475648);             // 134 MB
  unsigned short* wqh  = (unsigned short*)(ws + 446693376);    // 0.5 MB
  unsigned short* wql  = (unsigned short*)(ws + 447217664);
  unsigned short* wv   = (unsigned short*)(ws + 447741952);    // 2 MB
  unsigned short* wt1h = (unsigned short*)(ws + 449839104);
  unsigned short* wt1l = (unsigned short*)(ws + 450363392);
  unsigned short* wt2h = (unsigned short*)(ws + 450887680);
  unsigned short* wt2l = (unsigned short*)(ws + 451411968);
  unsigned short* wm1  = (unsigned short*)(ws + 451936256);    // 2 MB
  unsigned short* wm2  = (unsigned short*)(ws + 454033408);    // 2 MB (total ~456 MB)
  unsigned short* h2 = hhi;   // dead after xv gemm
  unsigned short* gb = hlo;   // dead after Qt gemm
  float* out = (float*)d_out;

  // weight converts
  cvt_kernel<<<dim3(256),  dim3(256), 0, stream>>>(qk_w, wqh, wql, 65536);
  cvt_kernel<<<dim3(1024), dim3(256), 0, stream>>>(v_w, wv, nullptr, 262144);
  cvt_kernel<<<dim3(256),  dim3(256), 0, stream>>>(t1_w, wt1h, wt1l, 65536);
  cvt_kernel<<<dim3(256),  dim3(256), 0, stream>>>(t2_w, wt2h, wt2l, 65536);
  cvt_kernel<<<dim3(1024), dim3(256), 0, stream>>>(m1_w, wm1, nullptr, 262144);
  cvt_kernel<<<dim3(1024), dim3(256), 0, stream>>>(m2_w, wm2, nullptr, 262144);
  // h = LN1(x) -> hi/lo
  ln_kernel<<<dim3(32768), dim3(256), 0, stream>>>(x, ln1_g, ln1_b, hhi, hlo);
  // Qt[b](256x4096) = qk_w @ h[b]^T   (split, hi/lo out)
  gemm_s<4><<<dim3(32, 2, 8), dim3(256), 0, stream>>>(
      wqh, wql, hhi, hlo, Qthi, Qtlo, nullptr,
      1024, 1024, 1024, 4096, 0, 4194304, 1048576, 1);
  // xv(32768x1024) = h @ v_w^T + v_b  (f16)
  gemm_v<0><<<dim3(4, 128, 1), dim3(512), 0, stream>>>(
      hhi, wv, xv, v_b, nullptr, 1024, 1024, 1024, 1024, 0, 0, 0, 0);
  // energy partials: part[b*8+s](256x256) = Qt[b] @ Qt[b]^T over k-chunk s
  gemm_s<5><<<dim3(2, 2, 64), dim3(256), 0, stream>>>(
      Qthi, Qtlo, Qthi, Qtlo, part, nullptr, nullptr,
      4096, 4096, 4096, 256, 1048576, 1048576, 65536, 8);
  ereduce_kernel<<<dim3(2048), dim3(256), 0, stream>>>(part, Ehi, Elo);
  // G[b](1024x256) = gelu(t1_w @ en[b] + t1_b)  (en symmetric -> NT; split out)
  gemm_s<6><<<dim3(2, 8, 8), dim3(256), 0, stream>>>(
      wt1h, wt1l, Ehi, Elo, Ghi, Glo, t1_b,
      256, 256, 256, 256, 0, 65536, 262144, 1);
  // a2[b](1024x1024) = t2_w @ G[b]^T + t2_b  (f32 out)
  gemm_s<7><<<dim3(8, 8, 8), dim3(256), 0, stream>>>(
      wt2h, wt2l, Ghi, Glo, a2, nullptr, t2_b,
      256, 256, 256, 1024, 0, 262144, 1048576, 1);
  // attT[b] = softmax(a2[b], -1)^T  (f16)
  smax_t_kernel<<<dim3(128, 8), dim3(256), 0, stream>>>(a2, attT);
  // x1[b](4096x1024,f32) = xv[b] @ attT[b]^T + x[b]
  gemm_v<2><<<dim3(4, 16, 8), dim3(512), 0, stream>>>(
      xv, attT, x1, nullptr, x, 1024, 1024, 1024, 1024, 4194304, 1048576, 4194304, 4194304);
  // h2 = LN2(x1) (f16 hi only)
  ln_kernel<<<dim3(32768), dim3(256), 0, stream>>>(x1, ln2_g, ln2_b, h2, nullptr);
  // g = gelu(h2 @ m1_w^T + m1_b)
  gemm_v<1><<<dim3(4, 128, 1), dim3(512), 0, stream>>>(
      h2, wm1, gb, m1_b, nullptr, 1024, 1024, 1024, 1024, 0, 0, 0, 0);
  // out = x1 + g @ m2_w^T + m2_b (f32)
  gemm_v<3><<<dim3(4, 128, 1), dim3(512), 0, stream>>>(
      gb, wm2, out, m2_b, x1, 1024, 1024, 1024, 1024, 0, 0, 0, 0);
}

// Round 7
// 712.933 us; speedup vs baseline: 1.4455x; 1.0108x over previous
//
#include <hip/hip_runtime.h>

// ---------------------------------------------------------------------------
// Enhanced_transformer  B=8, N=4096, P=1024, P4=256  (all fp32 in/out)
//
// Logit path (Qt, energy, G, a2): fp16-SPLIT MFMA (hi+lo, 3 MFMA/pair).
// Value path (xv, x1, m1, m2): plain f16 MFMA, 256^2 tile, 8 waves.
// R7: gemm_v = 4-buffer BK=32 deep pipeline (depth-3 prefetch, vmcnt(8),
// setprio around MFMA cluster) + LDS-staged coalesced f16 epilogue
// (kills the 2x write amplification seen in WRITE_SIZE).
// ---------------------------------------------------------------------------

typedef __attribute__((ext_vector_type(4))) float f32x4;
typedef __attribute__((ext_vector_type(8))) _Float16 h16x8;
typedef __attribute__((ext_vector_type(8))) unsigned short u16x8;
typedef __attribute__((ext_vector_type(4))) unsigned short u16x4;

__device__ __forceinline__ unsigned short f2h(float f) {
  _Float16 h = (_Float16)f;
  return __builtin_bit_cast(unsigned short, h);
}
// returns hi in bits[15:0], lo in bits[31:16]
__device__ __forceinline__ unsigned split16(float f) {
  _Float16 h = (_Float16)f;
  _Float16 l = (_Float16)(f - (float)h);
  return (unsigned)__builtin_bit_cast(unsigned short, h) |
         ((unsigned)__builtin_bit_cast(unsigned short, l) << 16);
}
__device__ __forceinline__ float gelu_f(float x) {
  return 0.5f * x * (1.0f + erff(x * 0.70710678118654752f));
}
__device__ __forceinline__ void gload16(const void* g, void* l) {
  __builtin_amdgcn_global_load_lds(
      (const __attribute__((address_space(1))) unsigned int*)g,
      (__attribute__((address_space(3))) unsigned int*)l, 16, 0, 0);
}
#define FENCE() asm volatile("" ::: "memory")

// ---------------- LayerNorm: row of 1024, out = f16 hi (+ optional lo) -----
__global__ __launch_bounds__(256)
void ln_kernel(const float* __restrict__ x, const float* __restrict__ g,
               const float* __restrict__ b, unsigned short* __restrict__ hi,
               unsigned short* __restrict__ lo) {
  __shared__ float red[16];
  const size_t base = (size_t)blockIdx.x * 1024;
  const int t = threadIdx.x;
  f32x4 v = *(const f32x4*)&x[base + t * 4];
  float s = v[0] + v[1] + v[2] + v[3];
  float q = v[0] * v[0] + v[1] * v[1] + v[2] * v[2] + v[3] * v[3];
#pragma unroll
  for (int o = 32; o > 0; o >>= 1) { s += __shfl_down(s, o); q += __shfl_down(q, o); }
  const int w = t >> 6;
  if ((t & 63) == 0) { red[w] = s; red[8 + w] = q; }
  __syncthreads();
  s = (red[0] + red[1]) + (red[2] + red[3]);
  q = (red[8] + red[9]) + (red[10] + red[11]);
  const float mu = s * (1.0f / 1024.0f);
  const float var = q * (1.0f / 1024.0f) - mu * mu;
  const float is = rsqrtf(var + 1e-5f);
  f32x4 gg = *(const f32x4*)&g[t * 4];
  f32x4 bb = *(const f32x4*)&b[t * 4];
  u16x4 oh, ol;
#pragma unroll
  for (int j = 0; j < 4; j++) {
    float y = (v[j] - mu) * is * gg[j] + bb[j];
    unsigned p = split16(y);
    oh[j] = (unsigned short)(p & 0xffffu);
    ol[j] = (unsigned short)(p >> 16);
  }
  *(u16x4*)&hi[base + t * 4] = oh;
  if (lo) *(u16x4*)&lo[base + t * 4] = ol;
}

// ---------------- fp32 -> f16 (hi + optional lo) ---------------------------
__global__ __launch_bounds__(256)
void cvt_kernel(const float* __restrict__ in, unsigned short* __restrict__ hi,
                unsigned short* __restrict__ lo, int n4) {
  int i = blockIdx.x * 256 + threadIdx.x;
  if (i < n4) {
    f32x4 v = *(const f32x4*)&in[(size_t)i * 4];
    u16x4 oh, ol;
#pragma unroll
    for (int j = 0; j < 4; j++) {
      unsigned p = split16(v[j]);
      oh[j] = (unsigned short)(p & 0xffffu);
      ol[j] = (unsigned short)(p >> 16);
    }
    *(u16x4*)&hi[(size_t)i * 4] = oh;
    if (lo) *(u16x4*)&lo[(size_t)i * 4] = ol;
  }
}

// ================= value-path GEMM: C = A(MxK) * B(NxK)^T ==================
// 256x256 tile, BK=32, 512 thr, 8 waves (2M x 4N), per-wave 128x64 out.
// 4 LDS buffers (16 KB A + 16 KB B each), prefetch depth 3, vmcnt(8) waits,
// setprio around the MFMA cluster, LDS-staged coalesced f16 epilogue.
// EPI: 0 f16 out +bias[col] | 1 f16 +bias +gelu | 2 f32 +res | 3 f32 +bias +res
template <int EPI>
__global__ __launch_bounds__(512, 1)
void gemm_v(const unsigned short* __restrict__ Ain, const unsigned short* __restrict__ Bin,
            void* __restrict__ Cout, const float* __restrict__ bias,
            const float* __restrict__ resIn,
            int K, int lda, int ldb, int ldc,
            long long sA, long long sB, long long sC, long long sRes) {
  __shared__ short LDSall[65536];                // 128 KB
  short* LA = LDSall;                            // 4 bufs x 8192 shorts (256x32)
  short* LB = LDSall + 32768;
  const int z = blockIdx.z;
  const unsigned short* A = Ain + (size_t)z * sA;
  const unsigned short* B = Bin + (size_t)z * sB;
  int bx = blockIdx.x, by = blockIdx.y;
  {
    const int nwg = gridDim.x * gridDim.y;
    if ((nwg & 7) == 0 && nwg >= 16) {
      const int flat = bx + gridDim.x * by;
      const int chunk = nwg >> 3;
      const int nf = (flat & 7) * chunk + (flat >> 3);
      bx = nf % gridDim.x;
      by = nf / gridDim.x;
    }
  }
  const int mBase = by * 256, nBase = bx * 256;
  const int t = threadIdx.x, w = t >> 6, l = t & 63;
  const int r16 = l & 15, kq = l >> 4;
  const int wr = (w >> 2) * 128, wc = (w & 3) * 64;
  f32x4 acc[8][4] = {};

  // stage one 256x32 A-tile + B-tile into buffer buf; 4 vmem instrs per wave
  auto stage = [&](int buf, int k0) {
#pragma unroll
    for (int i = 0; i < 2; ++i) {
      const int c = i * 512 + t;                 // chunk id (16B = 8 f16)
      const int row = c >> 2, cc = c & 3;
      const int gc = cc ^ ((row >> 1) & 3);      // source-side swizzle
      const int cb = i * 512 + w * 64;           // wave-uniform LDS base chunk
      gload16(&A[(size_t)(mBase + row) * lda + k0 + gc * 8], &LA[buf * 8192 + cb * 8]);
      gload16(&B[(size_t)(nBase + row) * ldb + k0 + gc * 8], &LB[buf * 8192 + cb * 8]);
    }
  };

  const int nt = K >> 5;                         // 32 steps at K=1024
  stage(0, 0);
  stage(1, 32);
  stage(2, 64);
  for (int ts = 0; ts < nt; ++ts) {
    const int buf = ts & 3;
    if (ts + 3 <= nt) { asm volatile("s_waitcnt vmcnt(8)" ::: "memory"); }
    else if (ts + 2 == nt) { asm volatile("s_waitcnt vmcnt(4)" ::: "memory"); }
    else { asm volatile("s_waitcnt vmcnt(0)" ::: "memory"); }
    __builtin_amdgcn_s_barrier();
    FENCE();
    __builtin_amdgcn_s_setprio(1);
    {
      h16x8 aF[8], bF[4];
#pragma unroll
      for (int ni = 0; ni < 4; ni++) {
        const int r = wc + ni * 16 + r16;
        bF[ni] = *(const h16x8*)&LB[buf * 8192 + r * 32 + ((kq ^ ((r >> 1) & 3))) * 8];
      }
#pragma unroll
      for (int mi = 0; mi < 8; mi++) {
        const int r = wr + mi * 16 + r16;
        aF[mi] = *(const h16x8*)&LA[buf * 8192 + r * 32 + ((kq ^ ((r >> 1) & 3))) * 8];
      }
#pragma unroll
      for (int mi = 0; mi < 8; mi++)
#pragma unroll
        for (int ni = 0; ni < 4; ni++)
          acc[mi][ni] = __builtin_amdgcn_mfma_f32_16x16x32_f16(aF[mi], bF[ni], acc[mi][ni], 0, 0, 0);
    }
    __builtin_amdgcn_s_setprio(0);
    FENCE();
    __builtin_amdgcn_s_barrier();
    FENCE();
    if (ts + 3 < nt) stage((ts + 3) & 3, (ts + 3) * 32);
  }

  unsigned short* C16 = (unsigned short*)Cout + (size_t)z * sC;
  float* C32 = (float*)Cout + (size_t)z * sC;
  const float* res = (EPI >= 2) ? (resIn + (size_t)z * sRes) : nullptr;

  if constexpr (EPI <= 1) {
    // f16 out: stage per-wave 128x64 tile in LDS, then coalesced u16x8 stores.
    short* ep = LDSall + w * 8192;               // 16 KB per wave, private
#pragma unroll
    for (int mi = 0; mi < 8; mi++) {
#pragma unroll
      for (int ni = 0; ni < 4; ni++) {
        const int cl = nBase + wc + ni * 16 + r16;
        const float bcol = bias[cl];
#pragma unroll
        for (int r = 0; r < 4; r++) {
          float v = acc[mi][ni][r] + bcol;
          if (EPI == 1) v = gelu_f(v);
          ep[(mi * 16 + kq * 4 + r) * 64 + ni * 16 + r16] = (short)f2h(v);
        }
      }
    }
    // same-wave LDS write->read ordering handled by compiler lgkmcnt
#pragma unroll
    for (int j = 0; j < 16; j++) {
      const int f = j * 512 + l * 8;             // flat idx in 128x64 tile
      const int row = f >> 6, col = f & 63;
      u16x8 v8 = *(const u16x8*)&ep[f];
      *(u16x8*)&C16[(size_t)(mBase + wr + row) * ldc + nBase + wc + col] = v8;
    }
  } else {
#pragma unroll
    for (int mi = 0; mi < 8; mi++) {
#pragma unroll
      for (int ni = 0; ni < 4; ni++) {
        const int cl = nBase + wc + ni * 16 + r16;
        const float bcol = (EPI == 3) ? bias[cl] : 0.0f;
#pragma unroll
        for (int r = 0; r < 4; r++) {
          const int rw = mBase + wr + mi * 16 + kq * 4 + r;
          float v = acc[mi][ni][r] + bcol + res[(size_t)rw * ldc + cl];
          C32[(size_t)rw * ldc + cl] = v;
        }
      }
    }
  }
}

// ================= split-path GEMM: C = A(MxK) * B(NxK)^T ==================
// fp16-split hi/lo, 128x128 tile, BK=32, 4 waves (2x2), dbuf LDS (64 KB),
// counted vmcnt(8) pipeline.
// EPI: 4 f16 hi/lo out | 5 f32 out | 6 f16 hi/lo +bias[row] +gelu | 7 f32 +bias[row]
template <int EPI>
__global__ __launch_bounds__(256)
void gemm_s(const unsigned short* __restrict__ Ahi, const unsigned short* __restrict__ Alo,
            const unsigned short* __restrict__ Bhi, const unsigned short* __restrict__ Blo,
            void* __restrict__ Cout, unsigned short* __restrict__ Cout2,
            const float* __restrict__ bias,
            int K, int lda, int ldb, int ldc,
            long long sA, long long sB, long long sC, int splitK) {
  __shared__ short As[2][8192];   // [buf][plane(hi 0 / lo 4096)][128x32]
  __shared__ short Bs[2][8192];
  const int z = blockIdx.z;
  const int bi = z / splitK, sp = z % splitK;
  const int kLen = K / splitK, kStart = sp * kLen;
  const unsigned short* AH = Ahi + (size_t)bi * sA;
  const unsigned short* BH = Bhi + (size_t)bi * sB;
  const unsigned short* AL = Alo + (size_t)bi * sA;
  const unsigned short* BL = Blo + (size_t)bi * sB;
  int bx = blockIdx.x, by = blockIdx.y;
  {
    const int nwg = gridDim.x * gridDim.y;
    if ((nwg & 7) == 0 && nwg >= 16) {
      const int flat = bx + gridDim.x * by;
      const int chunk = nwg >> 3;
      const int nf = (flat & 7) * chunk + (flat >> 3);
      bx = nf % gridDim.x;
      by = nf / gridDim.x;
    }
  }
  const int mBase = by * 128, nBase = bx * 128;
  const int t = threadIdx.x, w = t >> 6, l = t & 63;
  const int r16 = l & 15, kq = l >> 4;
  const int wr = (w >> 1) * 64, wc = (w & 1) * 64;
  f32x4 acc[4][4] = {};

  auto stage = [&](int buf, int k0) {   // 8 vector-mem instrs per wave
#pragma unroll
    for (int i = 0; i < 2; ++i) {
      const int c = i * 256 + t;             // chunk in 128x32 plane (512 chunks)
      const int row = c >> 2, cc = c & 3;
      const int gc = cc ^ ((row >> 1) & 3);  // source-side swizzle
      const int cbase = i * 256 + w * 64;    // wave-uniform
      const size_t ga = (size_t)(mBase + row) * lda + k0 + gc * 8;
      const size_t gb = (size_t)(nBase + row) * ldb + k0 + gc * 8;
      gload16(&AH[ga], &As[buf][cbase * 8]);
      gload16(&AL[ga], &As[buf][4096 + cbase * 8]);
      gload16(&BH[gb], &Bs[buf][cbase * 8]);
      gload16(&BL[gb], &Bs[buf][4096 + cbase * 8]);
    }
  };

  const int nsteps = kLen >> 5;
  stage(0, kStart);
  if (nsteps > 1) stage(1, kStart + 32);
  for (int ts = 0; ts < nsteps; ++ts) {
    const int cur = ts & 1;
    if (ts + 1 < nsteps) { asm volatile("s_waitcnt vmcnt(8)" ::: "memory"); }
    else                 { asm volatile("s_waitcnt vmcnt(0)" ::: "memory"); }
    __builtin_amdgcn_s_barrier();
    FENCE();
    h16x8 aH[4], bH[4], aL[4], bL[4];
#pragma unroll
    for (int mi = 0; mi < 4; mi++) {
      const int r = wr + mi * 16 + r16;
      const int off = r * 32 + (kq ^ ((r >> 1) & 3)) * 8;
      aH[mi] = *(const h16x8*)&As[cur][off];
      aL[mi] = *(const h16x8*)&As[cur][4096 + off];
    }
#pragma unroll
    for (int ni = 0; ni < 4; ni++) {
      const int r = wc + ni * 16 + r16;
      const int off = r * 32 + (kq ^ ((r >> 1) & 3)) * 8;
      bH[ni] = *(const h16x8*)&Bs[cur][off];
      bL[ni] = *(const h16x8*)&Bs[cur][4096 + off];
    }
    __builtin_amdgcn_s_setprio(1);
#pragma unroll
    for (int mi = 0; mi < 4; mi++)
#pragma unroll
      for (int ni = 0; ni < 4; ni++) {
        acc[mi][ni] = __builtin_amdgcn_mfma_f32_16x16x32_f16(aH[mi], bH[ni], acc[mi][ni], 0, 0, 0);
        acc[mi][ni] = __builtin_amdgcn_mfma_f32_16x16x32_f16(aH[mi], bL[ni], acc[mi][ni], 0, 0, 0);
        acc[mi][ni] = __builtin_amdgcn_mfma_f32_16x16x32_f16(aL[mi], bH[ni], acc[mi][ni], 0, 0, 0);
      }
    __builtin_amdgcn_s_setprio(0);
    FENCE();
    __builtin_amdgcn_s_barrier();
    FENCE();
    if (ts + 2 < nsteps) stage(cur, kStart + (ts + 2) * 32);
  }

  unsigned short* C16 = (unsigned short*)Cout + (size_t)z * sC;
  unsigned short* C16b = Cout2 ? Cout2 + (size_t)z * sC : nullptr;
  float* C32 = (float*)Cout + (size_t)z * sC;
#pragma unroll
  for (int mi = 0; mi < 4; mi++) {
#pragma unroll
    for (int ni = 0; ni < 4; ni++) {
      const int cl = nBase + wc + ni * 16 + r16;
#pragma unroll
      for (int r = 0; r < 4; r++) {
        const int rw = mBase + wr + mi * 16 + kq * 4 + r;
        float v = acc[mi][ni][r];
        if (EPI == 6 || EPI == 7) v += bias[rw];
        if (EPI == 6) v = gelu_f(v);
        const size_t idx = (size_t)rw * ldc + cl;
        if (EPI == 4 || EPI == 6) {
          unsigned p = split16(v);
          C16[idx] = (unsigned short)(p & 0xffffu);
          C16b[idx] = (unsigned short)(p >> 16);
        } else {
          C32[idx] = v;
        }
      }
    }
  }
}

// ---------------- energy split-K reduce -> f16 hi/lo -----------------------
__global__ __launch_bounds__(256)
void ereduce_kernel(const float* __restrict__ part, unsigned short* __restrict__ ehi,
                    unsigned short* __restrict__ elo) {
  const size_t idx = (size_t)blockIdx.x * 256 + threadIdx.x;  // 8*65536 total
  const size_t b = idx >> 16, i = idx & 65535;
  const float* p = part + b * (8ull * 65536) + i;
  float s0 = (p[0] + p[65536]) + (p[2 * 65536] + p[3 * 65536]);
  float s1 = (p[4 * 65536] + p[5 * 65536]) + (p[6 * 65536] + p[7 * 65536]);
  unsigned pk = split16(s0 + s1);
  ehi[idx] = (unsigned short)(pk & 0xffffu);
  elo[idx] = (unsigned short)(pk >> 16);
}

// ---------------- softmax over rows + transpose -> f16 ---------------------
__global__ __launch_bounds__(256)
void smax_t_kernel(const float* __restrict__ a2, unsigned short* __restrict__ attT) {
  __shared__ float S[8][1028];
  __shared__ float inv[8];
  const int t = threadIdx.x;
  const int b = blockIdx.y;
  const int o0 = blockIdx.x * 8;
  const float* src = a2 + ((size_t)b * 1024 + o0) * 1024;
#pragma unroll
  for (int i = 0; i < 8; i++)
    *(f32x4*)&S[i][t * 4] = *(const f32x4*)&src[(size_t)i * 1024 + t * 4];
  __syncthreads();
  const int w = t >> 6, l = t & 63;
  for (int rr = 0; rr < 2; rr++) {
    const int r = w * 2 + rr;
    float m = -1e30f;
#pragma unroll
    for (int i = 0; i < 16; i++) m = fmaxf(m, S[r][l + i * 64]);
#pragma unroll
    for (int o = 32; o > 0; o >>= 1) m = fmaxf(m, __shfl_xor(m, o));
    float ssum = 0.0f;
#pragma unroll
    for (int i = 0; i < 16; i++) {
      float e = expf(S[r][l + i * 64] - m);
      S[r][l + i * 64] = e;
      ssum += e;
    }
#pragma unroll
    for (int o = 32; o > 0; o >>= 1) ssum += __shfl_xor(ssum, o);
    if (l == 0) inv[r] = 1.0f / ssum;
  }
  __syncthreads();
  float iv[8];
#pragma unroll
  for (int r = 0; r < 8; r++) iv[r] = inv[r];
#pragma unroll
  for (int i = 0; i < 4; i++) {
    const int k = i * 256 + t;
    u16x8 ov;
#pragma unroll
    for (int r = 0; r < 8; r++) ov[r] = f2h(S[r][k] * iv[r]);
    *(u16x8*)&attT[((size_t)b * 1024 + k) * 1024 + o0] = ov;
  }
}

// ---------------------------------------------------------------------------
extern "C" void kernel_launch(void* const* d_in, const int* in_sizes, int n_in,
                              void* d_out, int out_size, void* d_ws, size_t ws_size,
                              hipStream_t stream) {
  (void)in_sizes; (void)n_in; (void)out_size; (void)ws_size;
  const float* x     = (const float*)d_in[1];
  const float* ln1_g = (const float*)d_in[2];
  const float* ln1_b = (const float*)d_in[3];
  const float* ln2_g = (const float*)d_in[4];
  const float* ln2_b = (const float*)d_in[5];
  const float* qk_w  = (const float*)d_in[6];
  const float* v_w   = (const float*)d_in[7];
  const float* v_b   = (const float*)d_in[8];
  const float* t1_w  = (const float*)d_in[9];
  const float* t1_b  = (const float*)d_in[10];
  const float* t2_w  = (const float*)d_in[11];
  const float* t2_b  = (const float*)d_in[12];
  const float* m1_w  = (const float*)d_in[13];
  const float* m1_b  = (const float*)d_in[14];
  const float* m2_w  = (const float*)d_in[15];
  const float* m2_b  = (const float*)d_in[16];

  char* ws = (char*)d_ws;
  unsigned short* hhi  = (unsigned short*)(ws + 0);            // 67 MB (-> h2)
  unsigned short* hlo  = (unsigned short*)(ws + 67108864);     // 67 MB (-> g)
  unsigned short* Qthi = (unsigned short*)(ws + 134217728);    // 16.8 MB
  unsigned short* Qtlo = (unsigned short*)(ws + 150994944);    // 16.8 MB
  float*          part = (float*)(ws + 167772160);             // 16.8 MB
  unsigned short* Ehi  = (unsigned short*)(ws + 184549376);    // 1 MB
  unsigned short* Elo  = (unsigned short*)(ws + 185597952);    // 1 MB
  unsigned short* Ghi  = (unsigned short*)(ws + 186646528);    // 4.2 MB
  unsigned short* Glo  = (unsigned short*)(ws + 190840832);    // 4.2 MB
  float*          a2   = (float*)(ws + 195035136);             // 33.5 MB
  unsigned short* attT = (unsigned short*)(ws + 228589568);    // 16.8 MB
  unsigned short* xv   = (unsigned short*)(ws + 245366784);    // 67 MB
  float*          x1   = (float*)(ws + 312475648);             // 134 MB
  unsigned short* wqh  = (unsigned short*)(ws + 446693376);    // 0.5 MB
  unsigned short* wql  = (unsigned short*)(ws + 447217664);
  unsigned short* wv   = (unsigned short*)(ws + 447741952);    // 2 MB
  unsigned short* wt1h = (unsigned short*)(ws + 449839104);
  unsigned short* wt1l = (unsigned short*)(ws + 450363392);
  unsigned short* wt2h = (unsigned short*)(ws + 450887680);
  unsigned short* wt2l = (unsigned short*)(ws + 451411968);
  unsigned short* wm1  = (unsigned short*)(ws + 451936256);    // 2 MB
  unsigned short* wm2  = (unsigned short*)(ws + 454033408);    // 2 MB (total ~456 MB)
  unsigned short* h2 = hhi;   // dead after xv gemm
  unsigned short* gb = hlo;   // dead after Qt gemm
  float* out = (float*)d_out;

  // weight converts
  cvt_kernel<<<dim3(256),  dim3(256), 0, stream>>>(qk_w, wqh, wql, 65536);
  cvt_kernel<<<dim3(1024), dim3(256), 0, stream>>>(v_w, wv, nullptr, 262144);
  cvt_kernel<<<dim3(256),  dim3(256), 0, stream>>>(t1_w, wt1h, wt1l, 65536);
  cvt_kernel<<<dim3(256),  dim3(256), 0, stream>>>(t2_w, wt2h, wt2l, 65536);
  cvt_kernel<<<dim3(1024), dim3(256), 0, stream>>>(m1_w, wm1, nullptr, 262144);
  cvt_kernel<<<dim3(1024), dim3(256), 0, stream>>>(m2_w, wm2, nullptr, 262144);
  // h = LN1(x) -> hi/lo
  ln_kernel<<<dim3(32768), dim3(256), 0, stream>>>(x, ln1_g, ln1_b, hhi, hlo);
  // Qt[b](256x4096) = qk_w @ h[b]^T   (split, hi/lo out)
  gemm_s<4><<<dim3(32, 2, 8), dim3(256), 0, stream>>>(
      wqh, wql, hhi, hlo, Qthi, Qtlo, nullptr,
      1024, 1024, 1024, 4096, 0, 4194304, 1048576, 1);
  // xv(32768x1024) = h @ v_w^T + v_b  (f16)
  gemm_v<0><<<dim3(4, 128, 1), dim3(512), 0, stream>>>(
      hhi, wv, xv, v_b, nullptr, 1024, 1024, 1024, 1024, 0, 0, 0, 0);
  // energy partials: part[b*8+s](256x256) = Qt[b] @ Qt[b]^T over k-chunk s
  gemm_s<5><<<dim3(2, 2, 64), dim3(256), 0, stream>>>(
      Qthi, Qtlo, Qthi, Qtlo, part, nullptr, nullptr,
      4096, 4096, 4096, 256, 1048576, 1048576, 65536, 8);
  ereduce_kernel<<<dim3(2048), dim3(256), 0, stream>>>(part, Ehi, Elo);
  // G[b](1024x256) = gelu(t1_w @ en[b] + t1_b)  (en symmetric -> NT; split out)
  gemm_s<6><<<dim3(2, 8, 8), dim3(256), 0, stream>>>(
      wt1h, wt1l, Ehi, Elo, Ghi, Glo, t1_b,
      256, 256, 256, 256, 0, 65536, 262144, 1);
  // a2[b](1024x1024) = t2_w @ G[b]^T + t2_b  (f32 out)
  gemm_s<7><<<dim3(8, 8, 8), dim3(256), 0, stream>>>(
      wt2h, wt2l, Ghi, Glo, a2, nullptr, t2_b,
      256, 256, 256, 1024, 0, 262144, 1048576, 1);
  // attT[b] = softmax(a2[b], -1)^T  (f16)
  smax_t_kernel<<<dim3(128, 8), dim3(256), 0, stream>>>(a2, attT);
  // x1[b](4096x1024,f32) = xv[b] @ attT[b]^T + x[b]
  gemm_v<2><<<dim3(4, 16, 8), dim3(512), 0, stream>>>(
      xv, attT, x1, nullptr, x, 1024, 1024, 1024, 1024, 4194304, 1048576, 4194304, 4194304);
  // h2 = LN2(x1) (f16 hi only)
  ln_kernel<<<dim3(32768), dim3(256), 0, stream>>>(x1, ln2_g, ln2_b, h2, nullptr);
  // g = gelu(h2 @ m1_w^T + m1_b)
  gemm_v<1><<<dim3(4, 128, 1), dim3(512), 0, stream>>>(
      h2, wm1, gb, m1_b, nullptr, 1024, 1024, 1024, 1024, 0, 0, 0, 0);
  // out = x1 + g @ m2_w^T + m2_b (f32)
  gemm_v<3><<<dim3(4, 128, 1), dim3(512), 0, stream>>>(
      gb, wm2, out, m2_b, x1, 1024, 1024, 1024, 1024, 0, 0, 0, 0);
}